// Round 4
// baseline (13211.887 us; speedup 1.0000x reference)
//
#include <hip/hip_runtime.h>

#define NREL 8

// ---------------------------------------------------------------------------
// Zero-fill kernels (hipMemsetAsync replacement: guaranteed graph-capturable,
// so every replay re-zeroes scratch/accumulators deterministically).
// n4 = number of float4 (16B) elements; buffers are all 16B-divisible.
// ---------------------------------------------------------------------------
__global__ __launch_bounds__(256) void zero16(float4* __restrict__ p, int n4)
{
    int i = blockIdx.x * 256 + threadIdx.x;
    int stride = gridDim.x * 256;
    for (; i < n4; i += stride) p[i] = make_float4(0.f, 0.f, 0.f, 0.f);
}

// ---------------------------------------------------------------------------
// cnt[r*N + dst] += 1 for each edge (for mean aggregation)
// ---------------------------------------------------------------------------
__global__ __launch_bounds__(256) void count_edges(
    const int* __restrict__ ei, const int* __restrict__ et,
    int* __restrict__ cnt, int E, int N)
{
    int e = blockIdx.x * 256 + threadIdx.x;
    if (e < E) {
        int d = ei[E + e];
        int r = et[e];
        atomicAdd(&cnt[r * N + d], 1);
    }
}

// ---------------------------------------------------------------------------
// Generic [Nrows,128] @ [128,128] fp32 GEMM.
//   O[n][j] = (agg ? agg[n][j] : 0) + sum_k X[n][k]*W[k][j] + (bias ? bias[j] : 0)
//   optional relu. W selected per blockIdx.y (wStride), output per oStride.
// BM=64 rows/block, 256 threads; each thread: 8 rows x 4 cols.
// LDS: xs 32KB + ws(64xK chunk) 32KB = 64KB -> 2 blocks/CU.
// ---------------------------------------------------------------------------
__global__ __launch_bounds__(256) void gemm128(
    const float* __restrict__ X, const float* __restrict__ Wb,
    const float* __restrict__ bias, const float* __restrict__ agg,
    float* __restrict__ outb, int Nrows, long long wStride, long long oStride,
    int relu)
{
    __shared__ float xs[64][128];
    __shared__ float ws[64][128];

    const float* W = Wb + (size_t)blockIdx.y * (size_t)wStride;
    float* O = outb + (size_t)blockIdx.y * (size_t)oStride;
    int row0 = blockIdx.x * 64;
    int t = threadIdx.x;

    // load X tile [64][128] (zero-pad OOB rows)
    {
        const float4* x4 = (const float4*)X;
        float4* xs4 = (float4*)&xs[0][0];
        #pragma unroll
        for (int i = t; i < 64 * 32; i += 256) {
            int rr = row0 + (i >> 5);
            float4 v = make_float4(0.f, 0.f, 0.f, 0.f);
            if (rr < Nrows) v = x4[(size_t)rr * 32 + (i & 31)];
            xs4[i] = v;
        }
    }

    int tx = t & 31;   // col group: cols 4*tx .. 4*tx+3
    int ty = t >> 5;   // row group: rows ty + 8*m, m=0..7
    float acc[8][4];
    #pragma unroll
    for (int m = 0; m < 8; m++)
        #pragma unroll
        for (int j = 0; j < 4; j++) acc[m][j] = 0.f;

    #pragma unroll
    for (int kb = 0; kb < 2; kb++) {
        // load W chunk rows [kb*64 .. kb*64+63]
        {
            const float4* w4 = (const float4*)(W + (size_t)kb * 64 * 128);
            float4* ws4 = (float4*)&ws[0][0];
            #pragma unroll
            for (int i = t; i < 2048; i += 256) ws4[i] = w4[i];
        }
        __syncthreads();

        #pragma unroll
        for (int k4 = 0; k4 < 16; k4++) {
            float4 wv[4];
            #pragma unroll
            for (int j = 0; j < 4; j++)
                wv[j] = *(const float4*)&ws[k4 * 4 + j][tx * 4];
            #pragma unroll
            for (int m = 0; m < 8; m++) {
                float4 xv = *(const float4*)&xs[ty + 8 * m][kb * 64 + k4 * 4];
                acc[m][0] += xv.x * wv[0].x + xv.y * wv[1].x + xv.z * wv[2].x + xv.w * wv[3].x;
                acc[m][1] += xv.x * wv[0].y + xv.y * wv[1].y + xv.z * wv[2].y + xv.w * wv[3].y;
                acc[m][2] += xv.x * wv[0].z + xv.y * wv[1].z + xv.z * wv[2].z + xv.w * wv[3].z;
                acc[m][3] += xv.x * wv[0].w + xv.y * wv[1].w + xv.z * wv[2].w + xv.w * wv[3].w;
            }
        }
        __syncthreads();
    }

    float4 bv = make_float4(0.f, 0.f, 0.f, 0.f);
    if (bias) bv = *(const float4*)&bias[tx * 4];

    #pragma unroll
    for (int m = 0; m < 8; m++) {
        int rr = row0 + ty + 8 * m;
        if (rr >= Nrows) continue;
        float4 o;
        o.x = acc[m][0] + bv.x;
        o.y = acc[m][1] + bv.y;
        o.z = acc[m][2] + bv.z;
        o.w = acc[m][3] + bv.w;
        if (agg) {
            float4 a = ((const float4*)(agg + (size_t)rr * 128))[tx];
            o.x += a.x; o.y += a.y; o.z += a.z; o.w += a.w;
        }
        if (relu) {
            o.x = fmaxf(o.x, 0.f); o.y = fmaxf(o.y, 0.f);
            o.z = fmaxf(o.z, 0.f); o.w = fmaxf(o.w, 0.f);
        }
        ((float4*)(O + (size_t)rr * 128))[tx] = o;
    }
}

// ---------------------------------------------------------------------------
// Per-edge scatter: agg[dst] += xW[rel][src] * (1/cnt[rel*N+dst])
// 1 wave per edge, float2 per lane. relFilter >= 0 -> only that relation
// (and xW is a single-relation buffer, relStride passed as 0).
// ---------------------------------------------------------------------------
__global__ __launch_bounds__(256) void scatter_edges(
    const float* __restrict__ xW, const int* __restrict__ ei,
    const int* __restrict__ et, const int* __restrict__ cnt,
    float* __restrict__ agg, int E, int N, long long relStride, int relFilter)
{
    int e = blockIdx.x * 4 + (threadIdx.x >> 6);
    int lane = threadIdx.x & 63;
    if (e >= E) return;
    int r = et[e];
    if (relFilter >= 0 && r != relFilter) return;
    int s = ei[e];
    int d = ei[E + e];
    float inv = 1.0f / (float)cnt[r * N + d];
    const float2 v =
        ((const float2*)(xW + (size_t)relStride * r + (size_t)s * 128))[lane];
    float* dp = agg + (size_t)d * 128 + lane * 2;
    atomicAdd(dp, v.x * inv);
    atomicAdd(dp + 1, v.y * inv);
}

// ---------------------------------------------------------------------------
// out[n][c] = sum_k emb[n][k] * Wc[k*16+c] + bc[c];   16 nodes / block
// ---------------------------------------------------------------------------
__global__ __launch_bounds__(256) void classifier(
    const float* __restrict__ emb, const float* __restrict__ Wc,
    const float* __restrict__ bc, float* __restrict__ out, int N)
{
    int t = threadIdx.x;
    int c = t & 15;
    int n = blockIdx.x * 16 + (t >> 4);
    if (n >= N) return;
    const float* e = emb + (size_t)n * 128;
    float acc = bc[c];
    #pragma unroll 8
    for (int k = 0; k < 128; k++) acc += e[k] * Wc[k * 16 + c];
    out[(size_t)n * 16 + c] = acc;
}

static inline size_t align256(size_t x) { return (x + 255) & ~(size_t)255; }

static inline int zgrid(long long n4)
{
    long long g = (n4 + 255) / 256;
    return (int)(g > 2048 ? 2048 : g);
}

extern "C" void kernel_launch(void* const* d_in, const int* in_sizes, int n_in,
                              void* d_out, int out_size, void* d_ws, size_t ws_size,
                              hipStream_t stream)
{
    const float* x     = (const float*)d_in[0];
    const int*   ei    = (const int*)d_in[1];
    const int*   et    = (const int*)d_in[2];
    const float* W1    = (const float*)d_in[3];
    const float* root1 = (const float*)d_in[4];
    const float* b1    = (const float*)d_in[5];
    const float* W2    = (const float*)d_in[6];
    const float* root2 = (const float*)d_in[7];
    const float* b2    = (const float*)d_in[8];
    const float* Wc    = (const float*)d_in[9];
    const float* bc    = (const float*)d_in[10];

    const int N = in_sizes[0] / 128;
    const int E = in_sizes[2];
    const int C = in_sizes[10];   // 16

    float* out = (float*)d_out;                 // [N,16]
    float* emb = out + (size_t)N * C;           // [N,128] (2nd output)

    // workspace layout
    size_t cntB = align256((size_t)NREL * N * sizeof(int));
    size_t hB   = align256((size_t)N * 128 * sizeof(float));
    size_t xwBigB   = (size_t)NREL * N * 128 * sizeof(float);

    char* p = (char*)d_ws;
    int*   cnt = (int*)p;
    float* h   = (float*)(p + cntB);
    float* xW  = (float*)(p + cntB + hB);
    const bool big = ws_size >= cntB + hB + xwBigB;

    const long long WSTR = 128 * 128;           // per-relation weight stride
    const long long NH   = (long long)N * 128;  // per-relation xW stride

    // zero-fill sizes in float4 units (all 16B-divisible)
    const long long cnt4 = (long long)NREL * N / 4;   // ints -> float4 count
    const long long nh4  = (long long)N * 128 / 4;

    dim3 blk(256);
    int gGemm = (N + 63) / 64;
    int gCnt  = (E + 255) / 256;
    int gScat = (E + 3) / 4;
    int gCls  = (N + 15) / 16;

    // edge counts (zero via kernel, NOT hipMemsetAsync: must be a graph node)
    zero16<<<zgrid(cnt4), blk, 0, stream>>>((float4*)cnt, (int)cnt4);
    count_edges<<<gCnt, blk, 0, stream>>>(ei, et, cnt, E, N);

    if (big) {
        // ---------------- layer 1 ----------------
        gemm128<<<dim3(gGemm, NREL), blk, 0, stream>>>(
            x, W1, nullptr, nullptr, xW, N, WSTR, NH, 0);
        zero16<<<zgrid(nh4), blk, 0, stream>>>((float4*)h, (int)nh4);
        scatter_edges<<<gScat, blk, 0, stream>>>(xW, ei, et, cnt, h, E, N, NH, -1);
        gemm128<<<dim3(gGemm, 1), blk, 0, stream>>>(
            x, root1, b1, h, h, N, 0, 0, 1);
        // ---------------- layer 2 ----------------
        gemm128<<<dim3(gGemm, NREL), blk, 0, stream>>>(
            h, W2, nullptr, nullptr, xW, N, WSTR, NH, 0);
        zero16<<<zgrid(nh4), blk, 0, stream>>>((float4*)emb, (int)nh4);
        scatter_edges<<<gScat, blk, 0, stream>>>(xW, ei, et, cnt, emb, E, N, NH, -1);
        gemm128<<<dim3(gGemm, 1), blk, 0, stream>>>(
            h, root2, b2, emb, emb, N, 0, 0, 0);
    } else {
        // per-relation fallback (xW holds one relation at a time)
        zero16<<<zgrid(nh4), blk, 0, stream>>>((float4*)h, (int)nh4);
        for (int r = 0; r < NREL; r++) {
            gemm128<<<dim3(gGemm, 1), blk, 0, stream>>>(
                x, W1 + (size_t)r * WSTR, nullptr, nullptr, xW, N, 0, 0, 0);
            scatter_edges<<<gScat, blk, 0, stream>>>(xW, ei, et, cnt, h, E, N, 0, r);
        }
        gemm128<<<dim3(gGemm, 1), blk, 0, stream>>>(
            x, root1, b1, h, h, N, 0, 0, 1);
        zero16<<<zgrid(nh4), blk, 0, stream>>>((float4*)emb, (int)nh4);
        for (int r = 0; r < NREL; r++) {
            gemm128<<<dim3(gGemm, 1), blk, 0, stream>>>(
                h, W2 + (size_t)r * WSTR, nullptr, nullptr, xW, N, 0, 0, 0);
            scatter_edges<<<gScat, blk, 0, stream>>>(xW, ei, et, cnt, emb, E, N, 0, r);
        }
        gemm128<<<dim3(gGemm, 1), blk, 0, stream>>>(
            h, root2, b2, emb, emb, N, 0, 0, 0);
    }

    // classifier
    classifier<<<gCls, blk, 0, stream>>>(emb, Wc, bc, out, N);
}

// Round 5
// 13149.046 us; speedup vs baseline: 1.0048x; 1.0048x over previous
//
#include <hip/hip_runtime.h>

#define NREL 8

// ---------------------------------------------------------------------------
// Zero-fill kernels (hipMemsetAsync replacement: guaranteed graph-capturable,
// so every replay re-zeroes scratch/accumulators deterministically).
// n4 = number of float4 (16B) elements; buffers are all 16B-divisible.
// ---------------------------------------------------------------------------
__global__ __launch_bounds__(256) void zero16(float4* __restrict__ p, int n4)
{
    int i = blockIdx.x * 256 + threadIdx.x;
    int stride = gridDim.x * 256;
    for (; i < n4; i += stride) p[i] = make_float4(0.f, 0.f, 0.f, 0.f);
}

// ---------------------------------------------------------------------------
// cnt[r*N + dst] += 1 for each edge (for mean aggregation)
// ---------------------------------------------------------------------------
__global__ __launch_bounds__(256) void count_edges(
    const int* __restrict__ ei, const int* __restrict__ et,
    int* __restrict__ cnt, int E, int N)
{
    int e = blockIdx.x * 256 + threadIdx.x;
    if (e < E) {
        int d = ei[E + e];
        int r = et[e];
        atomicAdd(&cnt[r * N + d], 1);
    }
}

// ---------------------------------------------------------------------------
// Generic [Nrows,128] @ [128,128] fp32 GEMM.
//   O[n][j] = (agg ? agg[n][j] : 0) + sum_k X[n][k]*W[k][j] + (bias ? bias[j] : 0)
//   optional relu. W selected per blockIdx.y (wStride), output per oStride.
// BM=64 rows/block, 256 threads; each thread: 8 rows x 4 cols.
// LDS: xs 32KB + ws(64xK chunk) 32KB = 64KB -> 2 blocks/CU.
// __launch_bounds__(256, 4): cap VGPRs at 128. Without the min-waves arg the
// allocator ran to the 256-VGPR cap and SPILLED the unrolled inner loop to
// scratch (round-4 profile: 9.7GB fetch + 7.4GB write per dispatch, VALUBusy
// 3.7%, 5.2ms). Natural pressure here is ~80 VGPRs, so 128 fits spill-free.
// ---------------------------------------------------------------------------
__global__ __launch_bounds__(256, 4) void gemm128(
    const float* __restrict__ X, const float* __restrict__ Wb,
    const float* __restrict__ bias, const float* __restrict__ agg,
    float* __restrict__ outb, int Nrows, long long wStride, long long oStride,
    int relu)
{
    __shared__ float xs[64][128];
    __shared__ float ws[64][128];

    const float* W = Wb + (size_t)blockIdx.y * (size_t)wStride;
    float* O = outb + (size_t)blockIdx.y * (size_t)oStride;
    int row0 = blockIdx.x * 64;
    int t = threadIdx.x;

    // load X tile [64][128] (zero-pad OOB rows)
    {
        const float4* x4 = (const float4*)X;
        float4* xs4 = (float4*)&xs[0][0];
        #pragma unroll
        for (int i = t; i < 64 * 32; i += 256) {
            int rr = row0 + (i >> 5);
            float4 v = make_float4(0.f, 0.f, 0.f, 0.f);
            if (rr < Nrows) v = x4[(size_t)rr * 32 + (i & 31)];
            xs4[i] = v;
        }
    }

    int tx = t & 31;   // col group: cols 4*tx .. 4*tx+3
    int ty = t >> 5;   // row group: rows ty + 8*m, m=0..7
    float acc[8][4];
    #pragma unroll
    for (int m = 0; m < 8; m++)
        #pragma unroll
        for (int j = 0; j < 4; j++) acc[m][j] = 0.f;

    #pragma unroll
    for (int kb = 0; kb < 2; kb++) {
        // load W chunk rows [kb*64 .. kb*64+63]
        {
            const float4* w4 = (const float4*)(W + (size_t)kb * 64 * 128);
            float4* ws4 = (float4*)&ws[0][0];
            #pragma unroll
            for (int i = t; i < 2048; i += 256) ws4[i] = w4[i];
        }
        __syncthreads();

        #pragma unroll
        for (int k4 = 0; k4 < 16; k4++) {
            float4 wv[4];
            #pragma unroll
            for (int j = 0; j < 4; j++)
                wv[j] = *(const float4*)&ws[k4 * 4 + j][tx * 4];
            #pragma unroll
            for (int m = 0; m < 8; m++) {
                float4 xv = *(const float4*)&xs[ty + 8 * m][kb * 64 + k4 * 4];
                acc[m][0] += xv.x * wv[0].x + xv.y * wv[1].x + xv.z * wv[2].x + xv.w * wv[3].x;
                acc[m][1] += xv.x * wv[0].y + xv.y * wv[1].y + xv.z * wv[2].y + xv.w * wv[3].y;
                acc[m][2] += xv.x * wv[0].z + xv.y * wv[1].z + xv.z * wv[2].z + xv.w * wv[3].z;
                acc[m][3] += xv.x * wv[0].w + xv.y * wv[1].w + xv.z * wv[2].w + xv.w * wv[3].w;
            }
        }
        __syncthreads();
    }

    float4 bv = make_float4(0.f, 0.f, 0.f, 0.f);
    if (bias) bv = *(const float4*)&bias[tx * 4];

    #pragma unroll
    for (int m = 0; m < 8; m++) {
        int rr = row0 + ty + 8 * m;
        if (rr >= Nrows) continue;
        float4 o;
        o.x = acc[m][0] + bv.x;
        o.y = acc[m][1] + bv.y;
        o.z = acc[m][2] + bv.z;
        o.w = acc[m][3] + bv.w;
        if (agg) {
            float4 a = ((const float4*)(agg + (size_t)rr * 128))[tx];
            o.x += a.x; o.y += a.y; o.z += a.z; o.w += a.w;
        }
        if (relu) {
            o.x = fmaxf(o.x, 0.f); o.y = fmaxf(o.y, 0.f);
            o.z = fmaxf(o.z, 0.f); o.w = fmaxf(o.w, 0.f);
        }
        ((float4*)(O + (size_t)rr * 128))[tx] = o;
    }
}

// ---------------------------------------------------------------------------
// Per-edge scatter: agg[dst] += xW[rel][src] * (1/cnt[rel*N+dst])
// 1 wave per edge, float2 per lane. relFilter >= 0 -> only that relation
// (and xW is a single-relation buffer, relStride passed as 0).
// ---------------------------------------------------------------------------
__global__ __launch_bounds__(256) void scatter_edges(
    const float* __restrict__ xW, const int* __restrict__ ei,
    const int* __restrict__ et, const int* __restrict__ cnt,
    float* __restrict__ agg, int E, int N, long long relStride, int relFilter)
{
    int e = blockIdx.x * 4 + (threadIdx.x >> 6);
    int lane = threadIdx.x & 63;
    if (e >= E) return;
    int r = et[e];
    if (relFilter >= 0 && r != relFilter) return;
    int s = ei[e];
    int d = ei[E + e];
    float inv = 1.0f / (float)cnt[r * N + d];
    const float2 v =
        ((const float2*)(xW + (size_t)relStride * r + (size_t)s * 128))[lane];
    float* dp = agg + (size_t)d * 128 + lane * 2;
    atomicAdd(dp, v.x * inv);
    atomicAdd(dp + 1, v.y * inv);
}

// ---------------------------------------------------------------------------
// out[n][c] = sum_k emb[n][k] * Wc[k*16+c] + bc[c];   16 nodes / block
// ---------------------------------------------------------------------------
__global__ __launch_bounds__(256) void classifier(
    const float* __restrict__ emb, const float* __restrict__ Wc,
    const float* __restrict__ bc, float* __restrict__ out, int N)
{
    int t = threadIdx.x;
    int c = t & 15;
    int n = blockIdx.x * 16 + (t >> 4);
    if (n >= N) return;
    const float* e = emb + (size_t)n * 128;
    float acc = bc[c];
    #pragma unroll 8
    for (int k = 0; k < 128; k++) acc += e[k] * Wc[k * 16 + c];
    out[(size_t)n * 16 + c] = acc;
}

static inline size_t align256(size_t x) { return (x + 255) & ~(size_t)255; }

static inline int zgrid(long long n4)
{
    long long g = (n4 + 255) / 256;
    return (int)(g > 2048 ? 2048 : g);
}

extern "C" void kernel_launch(void* const* d_in, const int* in_sizes, int n_in,
                              void* d_out, int out_size, void* d_ws, size_t ws_size,
                              hipStream_t stream)
{
    const float* x     = (const float*)d_in[0];
    const int*   ei    = (const int*)d_in[1];
    const int*   et    = (const int*)d_in[2];
    const float* W1    = (const float*)d_in[3];
    const float* root1 = (const float*)d_in[4];
    const float* b1    = (const float*)d_in[5];
    const float* W2    = (const float*)d_in[6];
    const float* root2 = (const float*)d_in[7];
    const float* b2    = (const float*)d_in[8];
    const float* Wc    = (const float*)d_in[9];
    const float* bc    = (const float*)d_in[10];

    const int N = in_sizes[0] / 128;
    const int E = in_sizes[2];
    const int C = in_sizes[10];   // 16

    float* out = (float*)d_out;                 // [N,16]
    float* emb = out + (size_t)N * C;           // [N,128] (2nd output)

    // workspace layout
    size_t cntB = align256((size_t)NREL * N * sizeof(int));
    size_t hB   = align256((size_t)N * 128 * sizeof(float));
    size_t xwBigB   = (size_t)NREL * N * 128 * sizeof(float);

    char* p = (char*)d_ws;
    int*   cnt = (int*)p;
    float* h   = (float*)(p + cntB);
    float* xW  = (float*)(p + cntB + hB);
    const bool big = ws_size >= cntB + hB + xwBigB;

    const long long WSTR = 128 * 128;           // per-relation weight stride
    const long long NH   = (long long)N * 128;  // per-relation xW stride

    // zero-fill sizes in float4 units (all 16B-divisible)
    const long long cnt4 = (long long)NREL * N / 4;   // ints -> float4 count
    const long long nh4  = (long long)N * 128 / 4;

    dim3 blk(256);
    int gGemm = (N + 63) / 64;
    int gCnt  = (E + 255) / 256;
    int gScat = (E + 3) / 4;
    int gCls  = (N + 15) / 16;

    // edge counts (zero via kernel, NOT hipMemsetAsync: must be a graph node)
    zero16<<<zgrid(cnt4), blk, 0, stream>>>((float4*)cnt, (int)cnt4);
    count_edges<<<gCnt, blk, 0, stream>>>(ei, et, cnt, E, N);

    if (big) {
        // ---------------- layer 1 ----------------
        gemm128<<<dim3(gGemm, NREL), blk, 0, stream>>>(
            x, W1, nullptr, nullptr, xW, N, WSTR, NH, 0);
        zero16<<<zgrid(nh4), blk, 0, stream>>>((float4*)h, (int)nh4);
        scatter_edges<<<gScat, blk, 0, stream>>>(xW, ei, et, cnt, h, E, N, NH, -1);
        gemm128<<<dim3(gGemm, 1), blk, 0, stream>>>(
            x, root1, b1, h, h, N, 0, 0, 1);
        // ---------------- layer 2 ----------------
        gemm128<<<dim3(gGemm, NREL), blk, 0, stream>>>(
            h, W2, nullptr, nullptr, xW, N, WSTR, NH, 0);
        zero16<<<zgrid(nh4), blk, 0, stream>>>((float4*)emb, (int)nh4);
        scatter_edges<<<gScat, blk, 0, stream>>>(xW, ei, et, cnt, emb, E, N, NH, -1);
        gemm128<<<dim3(gGemm, 1), blk, 0, stream>>>(
            h, root2, b2, emb, emb, N, 0, 0, 0);
    } else {
        // per-relation fallback (xW holds one relation at a time)
        zero16<<<zgrid(nh4), blk, 0, stream>>>((float4*)h, (int)nh4);
        for (int r = 0; r < NREL; r++) {
            gemm128<<<dim3(gGemm, 1), blk, 0, stream>>>(
                x, W1 + (size_t)r * WSTR, nullptr, nullptr, xW, N, 0, 0, 0);
            scatter_edges<<<gScat, blk, 0, stream>>>(xW, ei, et, cnt, h, E, N, 0, r);
        }
        gemm128<<<dim3(gGemm, 1), blk, 0, stream>>>(
            x, root1, b1, h, h, N, 0, 0, 1);
        zero16<<<zgrid(nh4), blk, 0, stream>>>((float4*)emb, (int)nh4);
        for (int r = 0; r < NREL; r++) {
            gemm128<<<dim3(gGemm, 1), blk, 0, stream>>>(
                h, W2 + (size_t)r * WSTR, nullptr, nullptr, xW, N, 0, 0, 0);
            scatter_edges<<<gScat, blk, 0, stream>>>(xW, ei, et, cnt, emb, E, N, 0, r);
        }
        gemm128<<<dim3(gGemm, 1), blk, 0, stream>>>(
            h, root2, b2, emb, emb, N, 0, 0, 0);
    }

    // classifier
    classifier<<<gCls, blk, 0, stream>>>(emb, Wc, bc, out, N);
}

// Round 6
// 1577.104 us; speedup vs baseline: 8.3773x; 8.3375x over previous
//
#include <hip/hip_runtime.h>

#define NREL 8

// ---------------------------------------------------------------------------
// Zero-fill kernels (hipMemsetAsync replacement: guaranteed graph-capturable,
// so every replay re-zeroes scratch/accumulators deterministically).
// n4 = number of float4 (16B) elements; buffers are all 16B-divisible.
// ---------------------------------------------------------------------------
__global__ __launch_bounds__(256) void zero16(float4* __restrict__ p, int n4)
{
    int i = blockIdx.x * 256 + threadIdx.x;
    int stride = gridDim.x * 256;
    for (; i < n4; i += stride) p[i] = make_float4(0.f, 0.f, 0.f, 0.f);
}

// ---------------------------------------------------------------------------
// cnt[r*N + dst] += 1 for each edge (for mean aggregation)
// ---------------------------------------------------------------------------
__global__ __launch_bounds__(256) void count_edges(
    const int* __restrict__ ei, const int* __restrict__ et,
    int* __restrict__ cnt, int E, int N)
{
    int e = blockIdx.x * 256 + threadIdx.x;
    if (e < E) {
        int d = ei[E + e];
        int r = et[e];
        atomicAdd(&cnt[r * N + d], 1);
    }
}

// ---------------------------------------------------------------------------
// Generic [Nrows,128] @ [128,128] fp32 GEMM.
//   O[n][j] = (agg ? agg[n][j] : 0) + sum_k X[n][k]*W[k][j] + (bias ? bias[j] : 0)
//   optional relu. W selected per blockIdx.y (wStride), output per oStride.
// BM=64 rows/block, 256 threads; each thread: 8 rows x 4 cols.
//
// ROUND-5 LESSON: full unroll of the 32 k-steps let the scheduler hoist
// hundreds of ds_read results -> VGPR demand >256 -> spill storm (9.7GB
// fetch / 7.4GB write per dispatch, VALUBusy 3.5%). launch_bounds alone
// could not fix it (VGPR stayed 256). Fix is STRUCTURAL: unroll 1 on the
// k4 loop bounds the live set to ~64-70 VGPR (acc 32 + wv 16 + xv 4 + addr).
// ---------------------------------------------------------------------------
__global__ __launch_bounds__(256, 4) void gemm128(
    const float* __restrict__ X, const float* __restrict__ Wb,
    const float* __restrict__ bias, const float* __restrict__ agg,
    float* __restrict__ outb, int Nrows, long long wStride, long long oStride,
    int relu)
{
    __shared__ float xs[64][128];
    __shared__ float ws[64][128];

    const float* W = Wb + (size_t)blockIdx.y * (size_t)wStride;
    float* O = outb + (size_t)blockIdx.y * (size_t)oStride;
    int row0 = blockIdx.x * 64;
    int t = threadIdx.x;

    // load X tile [64][128] (zero-pad OOB rows)
    {
        const float4* x4 = (const float4*)X;
        float4* xs4 = (float4*)&xs[0][0];
        #pragma unroll
        for (int i = t; i < 64 * 32; i += 256) {
            int rr = row0 + (i >> 5);
            float4 v = make_float4(0.f, 0.f, 0.f, 0.f);
            if (rr < Nrows) v = x4[(size_t)rr * 32 + (i & 31)];
            xs4[i] = v;
        }
    }

    int tx = t & 31;   // col group: cols 4*tx .. 4*tx+3
    int ty = t >> 5;   // row group: rows ty + 8*m, m=0..7
    float acc[8][4];
    #pragma unroll
    for (int m = 0; m < 8; m++)
        #pragma unroll
        for (int j = 0; j < 4; j++) acc[m][j] = 0.f;

    #pragma unroll 1
    for (int kb = 0; kb < 2; kb++) {
        // load W chunk rows [kb*64 .. kb*64+63]
        {
            const float4* w4 = (const float4*)(W + (size_t)kb * 64 * 128);
            float4* ws4 = (float4*)&ws[0][0];
            #pragma unroll
            for (int i = t; i < 2048; i += 256) ws4[i] = w4[i];
        }
        __syncthreads();

        #pragma unroll 1
        for (int k4 = 0; k4 < 16; k4++) {
            float4 wv[4];
            #pragma unroll
            for (int j = 0; j < 4; j++)
                wv[j] = *(const float4*)&ws[k4 * 4 + j][tx * 4];
            #pragma unroll
            for (int m = 0; m < 8; m++) {
                float4 xv = *(const float4*)&xs[ty + 8 * m][kb * 64 + k4 * 4];
                acc[m][0] += xv.x * wv[0].x + xv.y * wv[1].x + xv.z * wv[2].x + xv.w * wv[3].x;
                acc[m][1] += xv.x * wv[0].y + xv.y * wv[1].y + xv.z * wv[2].y + xv.w * wv[3].y;
                acc[m][2] += xv.x * wv[0].z + xv.y * wv[1].z + xv.z * wv[2].z + xv.w * wv[3].z;
                acc[m][3] += xv.x * wv[0].w + xv.y * wv[1].w + xv.z * wv[2].w + xv.w * wv[3].w;
            }
        }
        __syncthreads();
    }

    float4 bv = make_float4(0.f, 0.f, 0.f, 0.f);
    if (bias) bv = *(const float4*)&bias[tx * 4];

    #pragma unroll
    for (int m = 0; m < 8; m++) {
        int rr = row0 + ty + 8 * m;
        if (rr >= Nrows) continue;
        float4 o;
        o.x = acc[m][0] + bv.x;
        o.y = acc[m][1] + bv.y;
        o.z = acc[m][2] + bv.z;
        o.w = acc[m][3] + bv.w;
        if (agg) {
            float4 a = ((const float4*)(agg + (size_t)rr * 128))[tx];
            o.x += a.x; o.y += a.y; o.z += a.z; o.w += a.w;
        }
        if (relu) {
            o.x = fmaxf(o.x, 0.f); o.y = fmaxf(o.y, 0.f);
            o.z = fmaxf(o.z, 0.f); o.w = fmaxf(o.w, 0.f);
        }
        ((float4*)(O + (size_t)rr * 128))[tx] = o;
    }
}

// ---------------------------------------------------------------------------
// Per-edge scatter: agg[dst] += xW[rel][src] * (1/cnt[rel*N+dst])
// 1 wave per edge, float2 per lane. relFilter >= 0 -> only that relation
// (and xW is a single-relation buffer, relStride passed as 0).
// ---------------------------------------------------------------------------
__global__ __launch_bounds__(256) void scatter_edges(
    const float* __restrict__ xW, const int* __restrict__ ei,
    const int* __restrict__ et, const int* __restrict__ cnt,
    float* __restrict__ agg, int E, int N, long long relStride, int relFilter)
{
    int e = blockIdx.x * 4 + (threadIdx.x >> 6);
    int lane = threadIdx.x & 63;
    if (e >= E) return;
    int r = et[e];
    if (relFilter >= 0 && r != relFilter) return;
    int s = ei[e];
    int d = ei[E + e];
    float inv = 1.0f / (float)cnt[r * N + d];
    const float2 v =
        ((const float2*)(xW + (size_t)relStride * r + (size_t)s * 128))[lane];
    float* dp = agg + (size_t)d * 128 + lane * 2;
    atomicAdd(dp, v.x * inv);
    atomicAdd(dp + 1, v.y * inv);
}

// ---------------------------------------------------------------------------
// out[n][c] = sum_k emb[n][k] * Wc[k*16+c] + bc[c];   16 nodes / block
// ---------------------------------------------------------------------------
__global__ __launch_bounds__(256) void classifier(
    const float* __restrict__ emb, const float* __restrict__ Wc,
    const float* __restrict__ bc, float* __restrict__ out, int N)
{
    int t = threadIdx.x;
    int c = t & 15;
    int n = blockIdx.x * 16 + (t >> 4);
    if (n >= N) return;
    const float* e = emb + (size_t)n * 128;
    float acc = bc[c];
    #pragma unroll 8
    for (int k = 0; k < 128; k++) acc += e[k] * Wc[k * 16 + c];
    out[(size_t)n * 16 + c] = acc;
}

static inline size_t align256(size_t x) { return (x + 255) & ~(size_t)255; }

static inline int zgrid(long long n4)
{
    long long g = (n4 + 255) / 256;
    return (int)(g > 2048 ? 2048 : g);
}

extern "C" void kernel_launch(void* const* d_in, const int* in_sizes, int n_in,
                              void* d_out, int out_size, void* d_ws, size_t ws_size,
                              hipStream_t stream)
{
    const float* x     = (const float*)d_in[0];
    const int*   ei    = (const int*)d_in[1];
    const int*   et    = (const int*)d_in[2];
    const float* W1    = (const float*)d_in[3];
    const float* root1 = (const float*)d_in[4];
    const float* b1    = (const float*)d_in[5];
    const float* W2    = (const float*)d_in[6];
    const float* root2 = (const float*)d_in[7];
    const float* b2    = (const float*)d_in[8];
    const float* Wc    = (const float*)d_in[9];
    const float* bc    = (const float*)d_in[10];

    const int N = in_sizes[0] / 128;
    const int E = in_sizes[2];
    const int C = in_sizes[10];   // 16

    float* out = (float*)d_out;                 // [N,16]
    float* emb = out + (size_t)N * C;           // [N,128] (2nd output)

    // workspace layout
    size_t cntB = align256((size_t)NREL * N * sizeof(int));
    size_t hB   = align256((size_t)N * 128 * sizeof(float));
    size_t xwBigB   = (size_t)NREL * N * 128 * sizeof(float);

    char* p = (char*)d_ws;
    int*   cnt = (int*)p;
    float* h   = (float*)(p + cntB);
    float* xW  = (float*)(p + cntB + hB);
    const bool big = ws_size >= cntB + hB + xwBigB;

    const long long WSTR = 128 * 128;           // per-relation weight stride
    const long long NH   = (long long)N * 128;  // per-relation xW stride

    // zero-fill sizes in float4 units (all 16B-divisible)
    const long long cnt4 = (long long)NREL * N / 4;   // ints -> float4 count
    const long long nh4  = (long long)N * 128 / 4;

    dim3 blk(256);
    int gGemm = (N + 63) / 64;
    int gCnt  = (E + 255) / 256;
    int gScat = (E + 3) / 4;
    int gCls  = (N + 15) / 16;

    // edge counts (zero via kernel, NOT hipMemsetAsync: must be a graph node)
    zero16<<<zgrid(cnt4), blk, 0, stream>>>((float4*)cnt, (int)cnt4);
    count_edges<<<gCnt, blk, 0, stream>>>(ei, et, cnt, E, N);

    if (big) {
        // ---------------- layer 1 ----------------
        gemm128<<<dim3(gGemm, NREL), blk, 0, stream>>>(
            x, W1, nullptr, nullptr, xW, N, WSTR, NH, 0);
        zero16<<<zgrid(nh4), blk, 0, stream>>>((float4*)h, (int)nh4);
        scatter_edges<<<gScat, blk, 0, stream>>>(xW, ei, et, cnt, h, E, N, NH, -1);
        gemm128<<<dim3(gGemm, 1), blk, 0, stream>>>(
            x, root1, b1, h, h, N, 0, 0, 1);
        // ---------------- layer 2 ----------------
        gemm128<<<dim3(gGemm, NREL), blk, 0, stream>>>(
            h, W2, nullptr, nullptr, xW, N, WSTR, NH, 0);
        zero16<<<zgrid(nh4), blk, 0, stream>>>((float4*)emb, (int)nh4);
        scatter_edges<<<gScat, blk, 0, stream>>>(xW, ei, et, cnt, emb, E, N, NH, -1);
        gemm128<<<dim3(gGemm, 1), blk, 0, stream>>>(
            h, root2, b2, emb, emb, N, 0, 0, 0);
    } else {
        // per-relation fallback (xW holds one relation at a time)
        zero16<<<zgrid(nh4), blk, 0, stream>>>((float4*)h, (int)nh4);
        for (int r = 0; r < NREL; r++) {
            gemm128<<<dim3(gGemm, 1), blk, 0, stream>>>(
                x, W1 + (size_t)r * WSTR, nullptr, nullptr, xW, N, 0, 0, 0);
            scatter_edges<<<gScat, blk, 0, stream>>>(xW, ei, et, cnt, h, E, N, 0, r);
        }
        gemm128<<<dim3(gGemm, 1), blk, 0, stream>>>(
            x, root1, b1, h, h, N, 0, 0, 1);
        zero16<<<zgrid(nh4), blk, 0, stream>>>((float4*)emb, (int)nh4);
        for (int r = 0; r < NREL; r++) {
            gemm128<<<dim3(gGemm, 1), blk, 0, stream>>>(
                h, W2 + (size_t)r * WSTR, nullptr, nullptr, xW, N, 0, 0, 0);
            scatter_edges<<<gScat, blk, 0, stream>>>(xW, ei, et, cnt, emb, E, N, 0, r);
        }
        gemm128<<<dim3(gGemm, 1), blk, 0, stream>>>(
            h, root2, b2, emb, emb, N, 0, 0, 0);
    }

    // classifier
    classifier<<<gCls, blk, 0, stream>>>(emb, Wc, bc, out, N);
}

// Round 7
// 977.685 us; speedup vs baseline: 13.5134x; 1.6131x over previous
//
#include <hip/hip_runtime.h>

#define NREL 8

// ---------------------------------------------------------------------------
// zero16: graph-capturable memset replacement (round-2 lesson: hipMemsetAsync
// did not replay as a graph node -> stale state across timed replays).
// ---------------------------------------------------------------------------
__global__ __launch_bounds__(256) void zero16(float4* __restrict__ p, int n4)
{
    int i = blockIdx.x * 256 + threadIdx.x;
    int stride = gridDim.x * 256;
    for (; i < n4; i += stride) p[i] = make_float4(0.f, 0.f, 0.f, 0.f);
}

// ---------------------------------------------------------------------------
// cnt[r*N + dst] += 1 per edge (mean divisors, also feeds CSR row sizes)
// ---------------------------------------------------------------------------
__global__ __launch_bounds__(256) void count_edges(
    const int* __restrict__ ei, const int* __restrict__ et,
    int* __restrict__ cnt, int E, int N)
{
    int e = blockIdx.x * 256 + threadIdx.x;
    if (e < E) {
        int d = ei[E + e];
        int r = et[e];
        atomicAdd(&cnt[r * N + d], 1);
    }
}

// ---------------------------------------------------------------------------
// dcnt[d] = sum_r cnt[r*N+d]   (deterministic, no atomics)
// ---------------------------------------------------------------------------
__global__ __launch_bounds__(256) void dst_counts(
    const int* __restrict__ cnt, int* __restrict__ dcnt, int N)
{
    int d = blockIdx.x * 256 + threadIdx.x;
    if (d < N) {
        int s = 0;
        #pragma unroll
        for (int r = 0; r < NREL; r++) s += cnt[r * N + d];
        dcnt[d] = s;
    }
}

// ---------------------------------------------------------------------------
// Single-block exclusive scan of in[0..n) -> rowptr[0..n], cursor[0..n).
// in may alias cursor (read-before-write per chunk). 1024 threads,
// Hillis-Steele per 1024-chunk with running carry. n=50000 -> 49 chunks.
// ---------------------------------------------------------------------------
__global__ __launch_bounds__(1024) void exscan(
    const int* __restrict__ in, int* __restrict__ rowptr,
    int* __restrict__ cursor, int n)
{
    __shared__ int temp[1024];
    __shared__ int carry;
    int tid = threadIdx.x;
    if (tid == 0) carry = 0;
    __syncthreads();
    for (int base = 0; base < n; base += 1024) {
        int i = base + tid;
        int v = (i < n) ? in[i] : 0;
        temp[tid] = v;
        __syncthreads();
        for (int off = 1; off < 1024; off <<= 1) {
            int t = (tid >= off) ? temp[tid - off] : 0;
            __syncthreads();
            temp[tid] += t;
            __syncthreads();
        }
        int excl = temp[tid] - v + carry;     // reads old carry
        if (i < n) { rowptr[i] = excl; cursor[i] = excl; }
        int total = temp[1023];
        __syncthreads();                      // all reads of carry/temp done
        if (tid == 0) carry += total;
        __syncthreads();
    }
    if (tid == 0) rowptr[n] = carry;
}

// ---------------------------------------------------------------------------
// CSR fill: spk[pos] = src | (rel<<20) at pos = cursor[dst]++ (atomic).
// Order within a dst list is nondeterministic -> fp32 sum-order noise only.
// ---------------------------------------------------------------------------
__global__ __launch_bounds__(256) void fill_csr(
    const int* __restrict__ ei, const int* __restrict__ et,
    int* __restrict__ cursor, int* __restrict__ spk, int E)
{
    int e = blockIdx.x * 256 + threadIdx.x;
    if (e < E) {
        int d = ei[E + e];
        int pos = atomicAdd(&cursor[d], 1);
        spk[pos] = ei[e] | (et[e] << 20);
    }
}

// ---------------------------------------------------------------------------
// Gather-aggregate: one wave per dst. Walk CSR list, accumulate per-relation
// running sums of X[src] in registers (8 x float2 per lane), scale by 1/cnt,
// write aggX[r][dst] once. NO atomics; writes each output element exactly
// once (so no pre-zeroing of aggX needed).
// pk is wave-uniform -> switch(r) is a uniform branch (no divergence); static
// register targets (rule: runtime-indexed arrays spill to scratch).
// ---------------------------------------------------------------------------
__global__ __launch_bounds__(256) void gather_aggx(
    const float* __restrict__ X, const int* __restrict__ rowptr,
    const int* __restrict__ spk, const int* __restrict__ cnt,
    float* __restrict__ aggX, int N)
{
    int w = blockIdx.x * 4 + (threadIdx.x >> 6);
    if (w >= N) return;
    int lane = threadIdx.x & 63;

    float2 a0 = {0.f, 0.f}, a1 = {0.f, 0.f}, a2 = {0.f, 0.f}, a3 = {0.f, 0.f};
    float2 a4 = {0.f, 0.f}, a5 = {0.f, 0.f}, a6 = {0.f, 0.f}, a7 = {0.f, 0.f};

    int beg = rowptr[w], end = rowptr[w + 1];
    for (int i = beg; i < end; i++) {
        int pk = spk[i];
        int s = pk & 0xFFFFF;
        int r = pk >> 20;
        float2 v = ((const float2*)(X + (size_t)s * 128))[lane];
        switch (r) {
            case 0: a0.x += v.x; a0.y += v.y; break;
            case 1: a1.x += v.x; a1.y += v.y; break;
            case 2: a2.x += v.x; a2.y += v.y; break;
            case 3: a3.x += v.x; a3.y += v.y; break;
            case 4: a4.x += v.x; a4.y += v.y; break;
            case 5: a5.x += v.x; a5.y += v.y; break;
            case 6: a6.x += v.x; a6.y += v.y; break;
            default: a7.x += v.x; a7.y += v.y; break;
        }
    }

    #define WR(R, A)                                                        \
    {                                                                       \
        int c = cnt[R * N + w];                                             \
        float inv = (c > 0) ? 1.f / (float)c : 0.f;                         \
        ((float2*)(aggX + ((size_t)R * N + w) * 128))[lane] =               \
            make_float2(A.x * inv, A.y * inv);                              \
    }
    WR(0, a0) WR(1, a1) WR(2, a2) WR(3, a3)
    WR(4, a4) WR(5, a5) WR(6, a6) WR(7, a7)
    #undef WR
}

// ---------------------------------------------------------------------------
// Fused 9-source GEMM: O[n][j] = sum_{rs=0..7} aggX[rs][n][:]@Wrel[rs]
//                               + X[n][:]@root + bias[j], optional relu.
// K_eff = 1152. Same proven microkernel as round-6 gemm128: BM=64, 256 thr,
// 8x4 acc/thread, unroll-1 on all staged loops (round-5 lesson: full unroll
// -> VGPR>256 -> spill storm). In-place safe per-row (each block writes only
// the rows it alone reads), so layer-2 may run with X == O (h in emb).
// ---------------------------------------------------------------------------
__global__ __launch_bounds__(256, 4) void rgemm(
    const float* __restrict__ aggX, const float* __restrict__ X,
    const float* __restrict__ Wrel, const float* __restrict__ root,
    const float* __restrict__ bias, float* __restrict__ O,
    int Nrows, long long NH, int relu)
{
    __shared__ float xs[64][128];
    __shared__ float ws[64][128];

    int row0 = blockIdx.x * 64;
    int t = threadIdx.x;
    int tx = t & 31;   // cols 4*tx..4*tx+3
    int ty = t >> 5;   // rows ty + 8*m

    float acc[8][4];
    #pragma unroll
    for (int m = 0; m < 8; m++)
        #pragma unroll
        for (int j = 0; j < 4; j++) acc[m][j] = 0.f;

    #pragma unroll 1
    for (int rs = 0; rs < 9; rs++) {
        const float* A = (rs < 8) ? aggX + (size_t)rs * NH : X;
        const float* W = (rs < 8) ? Wrel + (size_t)rs * 16384 : root;

        // stage A tile [64][128] (prev iter's trailing sync protects xs)
        {
            const float4* x4 = (const float4*)A;
            float4* xs4 = (float4*)&xs[0][0];
            #pragma unroll 1
            for (int i = t; i < 64 * 32; i += 256) {
                int rr = row0 + (i >> 5);
                float4 v = make_float4(0.f, 0.f, 0.f, 0.f);
                if (rr < Nrows) v = x4[(size_t)rr * 32 + (i & 31)];
                xs4[i] = v;
            }
        }

        #pragma unroll 1
        for (int kb = 0; kb < 2; kb++) {
            {
                const float4* w4 = (const float4*)(W + (size_t)kb * 64 * 128);
                float4* ws4 = (float4*)&ws[0][0];
                #pragma unroll 1
                for (int i = t; i < 2048; i += 256) ws4[i] = w4[i];
            }
            __syncthreads();

            #pragma unroll 1
            for (int k4 = 0; k4 < 16; k4++) {
                float4 wv[4];
                #pragma unroll
                for (int j = 0; j < 4; j++)
                    wv[j] = *(const float4*)&ws[k4 * 4 + j][tx * 4];
                #pragma unroll
                for (int m = 0; m < 8; m++) {
                    float4 xv = *(const float4*)&xs[ty + 8 * m][kb * 64 + k4 * 4];
                    acc[m][0] += xv.x * wv[0].x + xv.y * wv[1].x + xv.z * wv[2].x + xv.w * wv[3].x;
                    acc[m][1] += xv.x * wv[0].y + xv.y * wv[1].y + xv.z * wv[2].y + xv.w * wv[3].y;
                    acc[m][2] += xv.x * wv[0].z + xv.y * wv[1].z + xv.z * wv[2].z + xv.w * wv[3].z;
                    acc[m][3] += xv.x * wv[0].w + xv.y * wv[1].w + xv.z * wv[2].w + xv.w * wv[3].w;
                }
            }
            __syncthreads();
        }
    }

    float4 bv = *(const float4*)&bias[tx * 4];

    #pragma unroll
    for (int m = 0; m < 8; m++) {
        int rr = row0 + ty + 8 * m;
        if (rr >= Nrows) continue;
        float4 o;
        o.x = acc[m][0] + bv.x;
        o.y = acc[m][1] + bv.y;
        o.z = acc[m][2] + bv.z;
        o.w = acc[m][3] + bv.w;
        if (relu) {
            o.x = fmaxf(o.x, 0.f); o.y = fmaxf(o.y, 0.f);
            o.z = fmaxf(o.z, 0.f); o.w = fmaxf(o.w, 0.f);
        }
        ((float4*)(O + (size_t)rr * 128))[tx] = o;
    }
}

// ---------------------------------------------------------------------------
// out[n][c] = sum_k emb[n][k] * Wc[k*16+c] + bc[c];   16 nodes / block
// ---------------------------------------------------------------------------
__global__ __launch_bounds__(256) void classifier(
    const float* __restrict__ emb, const float* __restrict__ Wc,
    const float* __restrict__ bc, float* __restrict__ out, int N)
{
    int t = threadIdx.x;
    int c = t & 15;
    int n = blockIdx.x * 16 + (t >> 4);
    if (n >= N) return;
    const float* e = emb + (size_t)n * 128;
    float acc = bc[c];
    #pragma unroll 8
    for (int k = 0; k < 128; k++) acc += e[k] * Wc[k * 16 + c];
    out[(size_t)n * 16 + c] = acc;
}

static inline size_t align256(size_t x) { return (x + 255) & ~(size_t)255; }

extern "C" void kernel_launch(void* const* d_in, const int* in_sizes, int n_in,
                              void* d_out, int out_size, void* d_ws, size_t ws_size,
                              hipStream_t stream)
{
    const float* x     = (const float*)d_in[0];
    const int*   ei    = (const int*)d_in[1];
    const int*   et    = (const int*)d_in[2];
    const float* W1    = (const float*)d_in[3];
    const float* root1 = (const float*)d_in[4];
    const float* b1    = (const float*)d_in[5];
    const float* W2    = (const float*)d_in[6];
    const float* root2 = (const float*)d_in[7];
    const float* b2    = (const float*)d_in[8];
    const float* Wc    = (const float*)d_in[9];
    const float* bc    = (const float*)d_in[10];

    const int N = in_sizes[0] / 128;
    const int E = in_sizes[2];
    const int C = in_sizes[10];   // 16

    float* out = (float*)d_out;                 // [N,16]
    float* emb = out + (size_t)N * C;           // [N,128] (2nd output); also h

    // workspace layout: cnt | rowptr | cursor | spk | aggX  (~209 MB)
    size_t cntB  = align256((size_t)NREL * N * sizeof(int));
    size_t rpB   = align256((size_t)(N + 1) * sizeof(int));
    size_t curB  = align256((size_t)N * sizeof(int));
    size_t spkB  = align256((size_t)E * sizeof(int));

    char* p = (char*)d_ws;
    int*   cnt    = (int*)p;                 p += cntB;
    int*   rowptr = (int*)p;                 p += rpB;
    int*   cursor = (int*)p;                 p += curB;
    int*   spk    = (int*)p;                 p += spkB;
    float* aggX   = (float*)p;

    const long long NH = (long long)N * 128;  // per-relation aggX stride

    dim3 blk(256);
    int gGemm = (N + 63) / 64;
    int gE    = (E + 255) / 256;
    int gN    = (N + 255) / 256;
    int gGat  = (N + 3) / 4;
    int gCls  = (N + 15) / 16;
    long long cnt4 = (long long)NREL * N / 4;
    int gZ = (int)((cnt4 + 255) / 256); if (gZ > 2048) gZ = 2048;

    // ---- CSR build (once; shared by both layers) ----
    zero16<<<gZ, blk, 0, stream>>>((float4*)cnt, (int)cnt4);
    count_edges<<<gE, blk, 0, stream>>>(ei, et, cnt, E, N);
    dst_counts<<<gN, blk, 0, stream>>>(cnt, cursor, N);          // cursor = dcnt
    exscan<<<1, 1024, 0, stream>>>(cursor, rowptr, cursor, N);   // in-place ok
    fill_csr<<<gE, blk, 0, stream>>>(ei, et, cursor, spk, E);

    // ---- layer 1 ----
    gather_aggx<<<gGat, blk, 0, stream>>>(x, rowptr, spk, cnt, aggX, N);
    rgemm<<<gGemm, blk, 0, stream>>>(aggX, x, W1, root1, b1, emb, N, NH, 1);

    // ---- layer 2 (h == emb; rgemm in-place per-row safe) ----
    gather_aggx<<<gGat, blk, 0, stream>>>(emb, rowptr, spk, cnt, aggX, N);
    rgemm<<<gGemm, blk, 0, stream>>>(aggX, emb, W2, root2, b2, emb, N, NH, 0);

    // ---- classifier ----
    classifier<<<gCls, blk, 0, stream>>>(emb, Wc, bc, out, N);
}

// Round 8
// 678.742 us; speedup vs baseline: 19.4653x; 1.4404x over previous
//
#include <hip/hip_runtime.h>

#define NREL 8

typedef __attribute__((ext_vector_type(8))) short bf16x8;
typedef __attribute__((ext_vector_type(4))) float f32x4;

__device__ inline ushort f2bf(float f)
{
    union { float f; unsigned u; } v; v.f = f;
    unsigned r = v.u + 0x7FFF + ((v.u >> 16) & 1);   // RNE
    return (ushort)(r >> 16);
}
__device__ inline float bf2f(ushort u)
{
    union { unsigned u; float f; } v; v.u = ((unsigned)u) << 16; return v.f;
}

// ---------------------------------------------------------------------------
// zero16: graph-capturable memset replacement (round-2 lesson).
// ---------------------------------------------------------------------------
__global__ __launch_bounds__(256) void zero16(float4* __restrict__ p, int n4)
{
    int i = blockIdx.x * 256 + threadIdx.x;
    int stride = gridDim.x * 256;
    for (; i < n4; i += stride) p[i] = make_float4(0.f, 0.f, 0.f, 0.f);
}

// ---------------------------------------------------------------------------
// CSR build chain (proven rounds 6-7): count -> dst totals -> scan -> fill
// ---------------------------------------------------------------------------
__global__ __launch_bounds__(256) void count_edges(
    const int* __restrict__ ei, const int* __restrict__ et,
    int* __restrict__ cnt, int E, int N)
{
    int e = blockIdx.x * 256 + threadIdx.x;
    if (e < E) {
        int d = ei[E + e];
        int r = et[e];
        atomicAdd(&cnt[r * N + d], 1);
    }
}

__global__ __launch_bounds__(256) void dst_counts(
    const int* __restrict__ cnt, int* __restrict__ dcnt, int N)
{
    int d = blockIdx.x * 256 + threadIdx.x;
    if (d < N) {
        int s = 0;
        #pragma unroll
        for (int r = 0; r < NREL; r++) s += cnt[r * N + d];
        dcnt[d] = s;
    }
}

__global__ __launch_bounds__(1024) void exscan(
    const int* __restrict__ in, int* __restrict__ rowptr,
    int* __restrict__ cursor, int n)
{
    __shared__ int temp[1024];
    __shared__ int carry;
    int tid = threadIdx.x;
    if (tid == 0) carry = 0;
    __syncthreads();
    for (int base = 0; base < n; base += 1024) {
        int i = base + tid;
        int v = (i < n) ? in[i] : 0;
        temp[tid] = v;
        __syncthreads();
        for (int off = 1; off < 1024; off <<= 1) {
            int t = (tid >= off) ? temp[tid - off] : 0;
            __syncthreads();
            temp[tid] += t;
            __syncthreads();
        }
        int excl = temp[tid] - v + carry;
        if (i < n) { rowptr[i] = excl; cursor[i] = excl; }
        int total = temp[1023];
        __syncthreads();
        if (tid == 0) carry += total;
        __syncthreads();
    }
    if (tid == 0) rowptr[n] = carry;
}

__global__ __launch_bounds__(256) void fill_csr(
    const int* __restrict__ ei, const int* __restrict__ et,
    int* __restrict__ cursor, int* __restrict__ spk, int E)
{
    int e = blockIdx.x * 256 + threadIdx.x;
    if (e < E) {
        int d = ei[E + e];
        int pos = atomicAdd(&cursor[d], 1);
        spk[pos] = ei[e] | (et[e] << 20);
    }
}

// ---------------------------------------------------------------------------
// fp32 -> bf16 converters.
// conv_x: activations, contiguous. conv_wt: weights to TRANSPOSED layout
// Wt[col][rs*128+k] so the MFMA B-fragment (col=lane&15, k contiguous 8)
// is one 16B load per lane.
// ---------------------------------------------------------------------------
__global__ __launch_bounds__(256) void conv_x(
    const float* __restrict__ x, ushort* __restrict__ xb, int n4)
{
    int i = blockIdx.x * 256 + threadIdx.x;
    int stride = gridDim.x * 256;
    for (; i < n4; i += stride) {
        float4 v = ((const float4*)x)[i];
        ushort4 o;
        o.x = f2bf(v.x); o.y = f2bf(v.y); o.z = f2bf(v.z); o.w = f2bf(v.w);
        ((ushort4*)xb)[i] = o;
    }
}

__global__ __launch_bounds__(256) void conv_wt(
    const float* __restrict__ W, const float* __restrict__ root,
    ushort* __restrict__ Wt)
{
    int i = blockIdx.x * 256 + threadIdx.x;   // i = col*1152 + kf
    if (i >= 128 * 1152) return;
    int col = i / 1152, kf = i - col * 1152;
    int rs = kf >> 7, k = kf & 127;
    float v = (rs < 8) ? W[rs * 16384 + k * 128 + col] : root[k * 128 + col];
    Wt[i] = f2bf(v);
}

// ---------------------------------------------------------------------------
// Gather-aggregate (bf16 in / bf16 out, fp32 accum): one wave per dst.
// Writes every aggX element exactly once -> no pre-zero. No atomics.
// ---------------------------------------------------------------------------
__global__ __launch_bounds__(256) void gather_aggx(
    const ushort* __restrict__ Xb, const int* __restrict__ rowptr,
    const int* __restrict__ spk, const int* __restrict__ cnt,
    ushort* __restrict__ aggX, int N)
{
    int w = blockIdx.x * 4 + (threadIdx.x >> 6);
    if (w >= N) return;
    int lane = threadIdx.x & 63;

    float2 a0 = {0.f, 0.f}, a1 = {0.f, 0.f}, a2 = {0.f, 0.f}, a3 = {0.f, 0.f};
    float2 a4 = {0.f, 0.f}, a5 = {0.f, 0.f}, a6 = {0.f, 0.f}, a7 = {0.f, 0.f};

    int beg = rowptr[w], end = rowptr[w + 1];
    for (int i = beg; i < end; i++) {
        int pk = spk[i];
        int s = pk & 0xFFFFF;
        int r = pk >> 20;
        unsigned u = ((const unsigned*)(Xb + (size_t)s * 128))[lane];
        float vx = bf2f((ushort)(u & 0xFFFF));
        float vy = bf2f((ushort)(u >> 16));
        switch (r) {
            case 0: a0.x += vx; a0.y += vy; break;
            case 1: a1.x += vx; a1.y += vy; break;
            case 2: a2.x += vx; a2.y += vy; break;
            case 3: a3.x += vx; a3.y += vy; break;
            case 4: a4.x += vx; a4.y += vy; break;
            case 5: a5.x += vx; a5.y += vy; break;
            case 6: a6.x += vx; a6.y += vy; break;
            default: a7.x += vx; a7.y += vy; break;
        }
    }

    #define WR(R, A)                                                        \
    {                                                                       \
        int c = cnt[R * N + w];                                             \
        float inv = (c > 0) ? 1.f / (float)c : 0.f;                         \
        ushort2 o; o.x = f2bf(A.x * inv); o.y = f2bf(A.y * inv);            \
        ((ushort2*)(aggX + ((size_t)R * N + w) * 128))[lane] = o;           \
    }
    WR(0, a0) WR(1, a1) WR(2, a2) WR(3, a3)
    WR(4, a4) WR(5, a5) WR(6, a6) WR(7, a7)
    #undef WR
}

// ---------------------------------------------------------------------------
// bf16 MFMA fused 9-source GEMM, LDS-free.
//   O[n][:] = concat_rs(aggX[rs][n][:], Xb[n][:]) @ Wt^T + bias, opt relu.
// Block = 256 thr = 4 waves; wave owns 16 rows x 128 cols. K = 9*128 = 1152.
// Fragments (mfma_f32_16x16x32_bf16):
//   A: row = lane&15, k = (lane>>4)*8 + j  -> 16B contiguous from row-major A
//   B: col = lane&15, k = (lane>>4)*8 + j  -> 16B contiguous from Wt[col][*]
//   D: col = lane&15, row = (lane>>4)*4 + reg   [guide §3, m89/m91-verified]
// kk unroll 2 bounds live B-frags (round-5 lesson: unbounded unroll = spill).
// ---------------------------------------------------------------------------
__global__ __launch_bounds__(256) void rgemm_mfma(
    const ushort* __restrict__ aggX,   // [8][N][128] bf16
    const ushort* __restrict__ Xb,     // [N][128] bf16 (source rs=8)
    const ushort* __restrict__ Wt,     // [128][1152] bf16 (col-major weights)
    const float* __restrict__ bias,    // [128] fp32
    float* __restrict__ Ofp,           // fp32 out (or null)
    ushort* __restrict__ Obf,          // bf16 out (or null)
    int N, int relu)
{
    int wid  = threadIdx.x >> 6;
    int lane = threadIdx.x & 63;
    int m0   = blockIdx.x * 64 + wid * 16;   // wave's first row
    int lrow = lane & 15;
    int kgrp = lane >> 4;                    // 0..3

    int arow = m0 + lrow;
    if (arow >= N) arow = N - 1;             // clamp (stores are guarded)

    f32x4 acc[8];
    #pragma unroll
    for (int n = 0; n < 8; n++) acc[n] = (f32x4){0.f, 0.f, 0.f, 0.f};

    #pragma unroll 1
    for (int rs = 0; rs < 9; rs++) {
        const ushort* A = (rs < 8) ? aggX + ((size_t)rs * N + arow) * 128
                                   : Xb + (size_t)arow * 128;
        const ushort* Bp = Wt + (size_t)lrow * 1152 + rs * 128 + kgrp * 8;

        #pragma unroll 2
        for (int kk = 0; kk < 4; kk++) {
            bf16x8 a = *(const bf16x8*)(A + kk * 32 + kgrp * 8);
            #pragma unroll
            for (int n = 0; n < 8; n++) {
                bf16x8 b = *(const bf16x8*)(Bp + (size_t)n * 16 * 1152 + kk * 32);
                acc[n] = __builtin_amdgcn_mfma_f32_16x16x32_bf16(a, b, acc[n], 0, 0, 0);
            }
        }
    }

    int row0 = m0 + kgrp * 4;
    #pragma unroll
    for (int n = 0; n < 8; n++) {
        int col = n * 16 + lrow;
        float bv = bias[col];
        #pragma unroll
        for (int r = 0; r < 4; r++) {
            int row = row0 + r;
            if (row >= N) continue;
            float v = acc[n][r] + bv;
            if (relu) v = fmaxf(v, 0.f);
            if (Ofp) Ofp[(size_t)row * 128 + col] = v;
            if (Obf) Obf[(size_t)row * 128 + col] = f2bf(v);
        }
    }
}

// ---------------------------------------------------------------------------
// out[n][c] = sum_k emb[n][k] * Wc[k*16+c] + bc[c];   16 nodes / block
// ---------------------------------------------------------------------------
__global__ __launch_bounds__(256) void classifier(
    const float* __restrict__ emb, const float* __restrict__ Wc,
    const float* __restrict__ bc, float* __restrict__ out, int N)
{
    int t = threadIdx.x;
    int c = t & 15;
    int n = blockIdx.x * 16 + (t >> 4);
    if (n >= N) return;
    const float* e = emb + (size_t)n * 128;
    float acc = bc[c];
    #pragma unroll 8
    for (int k = 0; k < 128; k++) acc += e[k] * Wc[k * 16 + c];
    out[(size_t)n * 16 + c] = acc;
}

static inline size_t align256(size_t x) { return (x + 255) & ~(size_t)255; }

extern "C" void kernel_launch(void* const* d_in, const int* in_sizes, int n_in,
                              void* d_out, int out_size, void* d_ws, size_t ws_size,
                              hipStream_t stream)
{
    const float* x     = (const float*)d_in[0];
    const int*   ei    = (const int*)d_in[1];
    const int*   et    = (const int*)d_in[2];
    const float* W1    = (const float*)d_in[3];
    const float* root1 = (const float*)d_in[4];
    const float* b1    = (const float*)d_in[5];
    const float* W2    = (const float*)d_in[6];
    const float* root2 = (const float*)d_in[7];
    const float* b2    = (const float*)d_in[8];
    const float* Wc    = (const float*)d_in[9];
    const float* bc    = (const float*)d_in[10];

    const int N = in_sizes[0] / 128;
    const int E = in_sizes[2];
    const int C = in_sizes[10];   // 16

    float* out = (float*)d_out;                 // [N,16]
    float* emb = out + (size_t)N * C;           // [N,128] fp32 (2nd output)

    // ws: cnt | rowptr | cursor | spk | aggX(bf16) | xb | hb | Wt1 | Wt2
    size_t cntB  = align256((size_t)NREL * N * sizeof(int));
    size_t rpB   = align256((size_t)(N + 1) * sizeof(int));
    size_t curB  = align256((size_t)N * sizeof(int));
    size_t spkB  = align256((size_t)E * sizeof(int));
    size_t aggB  = align256((size_t)NREL * N * 128 * sizeof(ushort));
    size_t xbB   = align256((size_t)N * 128 * sizeof(ushort));
    size_t wtB   = align256((size_t)128 * 1152 * sizeof(ushort));

    char* p = (char*)d_ws;
    int*    cnt    = (int*)p;      p += cntB;
    int*    rowptr = (int*)p;      p += rpB;
    int*    cursor = (int*)p;      p += curB;
    int*    spk    = (int*)p;      p += spkB;
    ushort* aggX   = (ushort*)p;   p += aggB;
    ushort* xb     = (ushort*)p;   p += xbB;
    ushort* hb     = (ushort*)p;   p += xbB;
    ushort* Wt1    = (ushort*)p;   p += wtB;
    ushort* Wt2    = (ushort*)p;

    dim3 blk(256);
    int gE    = (E + 255) / 256;
    int gN    = (N + 255) / 256;
    int gGat  = (N + 3) / 4;
    int gGemm = (N + 63) / 64;
    int gCls  = (N + 15) / 16;
    int gWt   = (128 * 1152 + 255) / 256;
    long long cnt4 = (long long)NREL * N / 4;
    int gZ = (int)((cnt4 + 255) / 256); if (gZ > 2048) gZ = 2048;
    int nx4 = N * 32;                       // N*128/4 float4 groups
    int gCx = (nx4 + 255) / 256; if (gCx > 2048) gCx = 2048;

    // ---- CSR build (shared by both layers) ----
    zero16<<<gZ, blk, 0, stream>>>((float4*)cnt, (int)cnt4);
    count_edges<<<gE, blk, 0, stream>>>(ei, et, cnt, E, N);
    dst_counts<<<gN, blk, 0, stream>>>(cnt, cursor, N);
    exscan<<<1, 1024, 0, stream>>>(cursor, rowptr, cursor, N);
    fill_csr<<<gE, blk, 0, stream>>>(ei, et, cursor, spk, E);

    // ---- bf16 conversions ----
    conv_x<<<gCx, blk, 0, stream>>>(x, xb, nx4);
    conv_wt<<<gWt, blk, 0, stream>>>(W1, root1, Wt1);
    conv_wt<<<gWt, blk, 0, stream>>>(W2, root2, Wt2);

    // ---- layer 1: gather + MFMA GEMM -> hb (bf16, relu) ----
    gather_aggx<<<gGat, blk, 0, stream>>>(xb, rowptr, spk, cnt, aggX, N);
    rgemm_mfma<<<gGemm, blk, 0, stream>>>(aggX, xb, Wt1, b1,
                                          nullptr, hb, N, 1);

    // ---- layer 2: gather + MFMA GEMM -> emb (fp32) ----
    gather_aggx<<<gGat, blk, 0, stream>>>(hb, rowptr, spk, cnt, aggX, N);
    rgemm_mfma<<<gGemm, blk, 0, stream>>>(aggX, hb, Wt2, b2,
                                          emb, nullptr, N, 0);

    // ---- classifier ----
    classifier<<<gCls, blk, 0, stream>>>(emb, Wc, bc, out, N);
}

// Round 9
// 495.422 us; speedup vs baseline: 26.6680x; 1.3700x over previous
//
#include <hip/hip_runtime.h>

#define NREL 8

typedef __attribute__((ext_vector_type(8))) short bf16x8;
typedef __attribute__((ext_vector_type(4))) float f32x4;

__device__ inline ushort f2bf(float f)
{
    union { float f; unsigned u; } v; v.f = f;
    unsigned r = v.u + 0x7FFF + ((v.u >> 16) & 1);   // RNE
    return (ushort)(r >> 16);
}
__device__ inline float bf2f(ushort u)
{
    union { unsigned u; float f; } v; v.u = ((unsigned)u) << 16; return v.f;
}

// ---------------------------------------------------------------------------
// zero16: graph-capturable memset replacement (round-2 lesson).
// ---------------------------------------------------------------------------
__global__ __launch_bounds__(256) void zero16(float4* __restrict__ p, int n4)
{
    int i = blockIdx.x * 256 + threadIdx.x;
    int stride = gridDim.x * 256;
    for (; i < n4; i += stride) p[i] = make_float4(0.f, 0.f, 0.f, 0.f);
}

// ---------------------------------------------------------------------------
// CSR build chain (proven rounds 6-8)
// ---------------------------------------------------------------------------
__global__ __launch_bounds__(256) void count_edges(
    const int* __restrict__ ei, const int* __restrict__ et,
    int* __restrict__ cnt, int E, int N)
{
    int e = blockIdx.x * 256 + threadIdx.x;
    if (e < E) {
        int d = ei[E + e];
        int r = et[e];
        atomicAdd(&cnt[r * N + d], 1);
    }
}

__global__ __launch_bounds__(256) void dst_counts(
    const int* __restrict__ cnt, int* __restrict__ dcnt, int N)
{
    int d = blockIdx.x * 256 + threadIdx.x;
    if (d < N) {
        int s = 0;
        #pragma unroll
        for (int r = 0; r < NREL; r++) s += cnt[r * N + d];
        dcnt[d] = s;
    }
}

__global__ __launch_bounds__(1024) void exscan(
    const int* __restrict__ in, int* __restrict__ rowptr,
    int* __restrict__ cursor, int n)
{
    __shared__ int temp[1024];
    __shared__ int carry;
    int tid = threadIdx.x;
    if (tid == 0) carry = 0;
    __syncthreads();
    for (int base = 0; base < n; base += 1024) {
        int i = base + tid;
        int v = (i < n) ? in[i] : 0;
        temp[tid] = v;
        __syncthreads();
        for (int off = 1; off < 1024; off <<= 1) {
            int t = (tid >= off) ? temp[tid - off] : 0;
            __syncthreads();
            temp[tid] += t;
            __syncthreads();
        }
        int excl = temp[tid] - v + carry;
        if (i < n) { rowptr[i] = excl; cursor[i] = excl; }
        int total = temp[1023];
        __syncthreads();
        if (tid == 0) carry += total;
        __syncthreads();
    }
    if (tid == 0) rowptr[n] = carry;
}

__global__ __launch_bounds__(256) void fill_csr(
    const int* __restrict__ ei, const int* __restrict__ et,
    int* __restrict__ cursor, int* __restrict__ spk, int E)
{
    int e = blockIdx.x * 256 + threadIdx.x;
    if (e < E) {
        int d = ei[E + e];
        int pos = atomicAdd(&cursor[d], 1);
        spk[pos] = ei[e] | (et[e] << 20);
    }
}

// ---------------------------------------------------------------------------
// conv_x: fp32 activations -> bf16, contiguous.
// ---------------------------------------------------------------------------
__global__ __launch_bounds__(256) void conv_x(
    const float* __restrict__ x, ushort* __restrict__ xb, int n4)
{
    int i = blockIdx.x * 256 + threadIdx.x;
    int stride = gridDim.x * 256;
    for (; i < n4; i += stride) {
        float4 v = ((const float4*)x)[i];
        ushort4 o;
        o.x = f2bf(v.x); o.y = f2bf(v.y); o.z = f2bf(v.z); o.w = f2bf(v.w);
        ((ushort4*)xb)[i] = o;
    }
}

// ---------------------------------------------------------------------------
// conv_wf: weights -> bf16 in MFMA-FRAGMENT order.
// Wf[f*512 + lane*8 + j], f = (rs*4 + kk)*8 + n, holds B[col][k] with
//   col = n*16 + (lane&15), k_local = kk*32 + (lane>>4)*8 + j.
// A wave's B-fragment load is then Wf8[f*64 + lane]: 64 lanes x 16B fully
// contiguous (1KB, one transaction) and L2-resident (294KB total).
// Round-8 lesson: lrow-strided loads split into 16 lines AND VGPR=40 meant
// zero load batching -> ~1100 cyc/load serial latency, MfmaUtil 3.7%.
// ---------------------------------------------------------------------------
__global__ __launch_bounds__(256) void conv_wf(
    const float* __restrict__ W, const float* __restrict__ root,
    ushort* __restrict__ Wf)
{
    int i = blockIdx.x * 256 + threadIdx.x;   // one thread per output ushort
    if (i >= 128 * 1152) return;
    int f = i >> 9;             // fragment index
    int within = i & 511;
    int l = within >> 3;        // lane
    int j = within & 7;
    int rs = f >> 5;
    int kk = (f >> 3) & 3;
    int n  = f & 7;
    int col = (n << 4) | (l & 15);
    int kl  = kk * 32 + (l >> 4) * 8 + j;     // 0..127
    float v = (rs < 8) ? W[rs * 16384 + kl * 128 + col] : root[kl * 128 + col];
    Wf[i] = f2bf(v);
}

// ---------------------------------------------------------------------------
// Gather-aggregate (bf16 in / bf16 out, fp32 accum): one wave per dst.
// ---------------------------------------------------------------------------
__global__ __launch_bounds__(256) void gather_aggx(
    const ushort* __restrict__ Xb, const int* __restrict__ rowptr,
    const int* __restrict__ spk, const int* __restrict__ cnt,
    ushort* __restrict__ aggX, int N)
{
    int w = blockIdx.x * 4 + (threadIdx.x >> 6);
    if (w >= N) return;
    int lane = threadIdx.x & 63;

    float2 a0 = {0.f, 0.f}, a1 = {0.f, 0.f}, a2 = {0.f, 0.f}, a3 = {0.f, 0.f};
    float2 a4 = {0.f, 0.f}, a5 = {0.f, 0.f}, a6 = {0.f, 0.f}, a7 = {0.f, 0.f};

    int beg = rowptr[w], end = rowptr[w + 1];
    for (int i = beg; i < end; i++) {
        int pk = spk[i];
        int s = pk & 0xFFFFF;
        int r = pk >> 20;
        unsigned u = ((const unsigned*)(Xb + (size_t)s * 128))[lane];
        float vx = bf2f((ushort)(u & 0xFFFF));
        float vy = bf2f((ushort)(u >> 16));
        switch (r) {
            case 0: a0.x += vx; a0.y += vy; break;
            case 1: a1.x += vx; a1.y += vy; break;
            case 2: a2.x += vx; a2.y += vy; break;
            case 3: a3.x += vx; a3.y += vy; break;
            case 4: a4.x += vx; a4.y += vy; break;
            case 5: a5.x += vx; a5.y += vy; break;
            case 6: a6.x += vx; a6.y += vy; break;
            default: a7.x += vx; a7.y += vy; break;
        }
    }

    #define WR(R, A)                                                        \
    {                                                                       \
        int c = cnt[R * N + w];                                             \
        float inv = (c > 0) ? 1.f / (float)c : 0.f;                         \
        ushort2 o; o.x = f2bf(A.x * inv); o.y = f2bf(A.y * inv);            \
        ((ushort2*)(aggX + ((size_t)R * N + w) * 128))[lane] = o;           \
    }
    WR(0, a0) WR(1, a1) WR(2, a2) WR(3, a3)
    WR(4, a4) WR(5, a5) WR(6, a6) WR(7, a7)
    #undef WR
}

// ---------------------------------------------------------------------------
// bf16 MFMA fused 9-source GEMM, LDS-free, fragment-ordered B.
// Named b0..b7 FORCE 8 loads in flight before the MFMA group (round-8
// lesson: letting the compiler minimize registers (VGPR=40) serialized
// load->mfma 1:1 at full L2/L3 latency). Live set ~120 VGPR: bounded.
// ---------------------------------------------------------------------------
__global__ __launch_bounds__(256) void rgemm_mfma(
    const ushort* __restrict__ aggX,   // [8][N][128] bf16
    const ushort* __restrict__ Xb,     // [N][128] bf16 (source rs=8)
    const ushort* __restrict__ Wf,     // fragment-ordered weights (294KB)
    const float* __restrict__ bias,    // [128] fp32
    float* __restrict__ Ofp,           // fp32 out (or null)
    ushort* __restrict__ Obf,          // bf16 out (or null)
    int N, int relu)
{
    int wid  = threadIdx.x >> 6;
    int lane = threadIdx.x & 63;
    int m0   = blockIdx.x * 64 + wid * 16;   // wave's first row
    int lrow = lane & 15;
    int kgrp = lane >> 4;                    // 0..3

    int arow = m0 + lrow;
    if (arow >= N) arow = N - 1;             // clamp (stores are guarded)

    const bf16x8* Wf8 = (const bf16x8*)Wf;   // 64 frags of bf16x8 per (rs,kk,n=0..7)

    f32x4 acc[8];
    #pragma unroll
    for (int n = 0; n < 8; n++) acc[n] = (f32x4){0.f, 0.f, 0.f, 0.f};

    #pragma unroll 1
    for (int rs = 0; rs < 9; rs++) {
        const ushort* A = (rs < 8) ? aggX + ((size_t)rs * N + arow) * 128
                                   : Xb + (size_t)arow * 128;
        const bf16x8* Bp = Wf8 + (size_t)rs * 2048 + lane;   // 4*8*64 frags/rs

        #pragma unroll 2
        for (int kk = 0; kk < 4; kk++) {
            bf16x8 a = *(const bf16x8*)(A + kk * 32 + kgrp * 8);
            const bf16x8* bq = Bp + kk * 512;                 // 8*64 per kk
            bf16x8 b0 = bq[0];
            bf16x8 b1 = bq[64];
            bf16x8 b2 = bq[128];
            bf16x8 b3 = bq[192];
            bf16x8 b4 = bq[256];
            bf16x8 b5 = bq[320];
            bf16x8 b6 = bq[384];
            bf16x8 b7 = bq[448];
            acc[0] = __builtin_amdgcn_mfma_f32_16x16x32_bf16(a, b0, acc[0], 0, 0, 0);
            acc[1] = __builtin_amdgcn_mfma_f32_16x16x32_bf16(a, b1, acc[1], 0, 0, 0);
            acc[2] = __builtin_amdgcn_mfma_f32_16x16x32_bf16(a, b2, acc[2], 0, 0, 0);
            acc[3] = __builtin_amdgcn_mfma_f32_16x16x32_bf16(a, b3, acc[3], 0, 0, 0);
            acc[4] = __builtin_amdgcn_mfma_f32_16x16x32_bf16(a, b4, acc[4], 0, 0, 0);
            acc[5] = __builtin_amdgcn_mfma_f32_16x16x32_bf16(a, b5, acc[5], 0, 0, 0);
            acc[6] = __builtin_amdgcn_mfma_f32_16x16x32_bf16(a, b6, acc[6], 0, 0, 0);
            acc[7] = __builtin_amdgcn_mfma_f32_16x16x32_bf16(a, b7, acc[7], 0, 0, 0);
        }
    }

    int row0 = m0 + kgrp * 4;
    #pragma unroll
    for (int n = 0; n < 8; n++) {
        int col = n * 16 + lrow;
        float bv = bias[col];
        #pragma unroll
        for (int r = 0; r < 4; r++) {
            int row = row0 + r;
            if (row >= N) continue;
            float v = acc[n][r] + bv;
            if (relu) v = fmaxf(v, 0.f);
            if (Ofp) Ofp[(size_t)row * 128 + col] = v;
            if (Obf) Obf[(size_t)row * 128 + col] = f2bf(v);
        }
    }
}

// ---------------------------------------------------------------------------
// out[n][c] = sum_k emb[n][k] * Wc[k*16+c] + bc[c];   16 nodes / block
// ---------------------------------------------------------------------------
__global__ __launch_bounds__(256) void classifier(
    const float* __restrict__ emb, const float* __restrict__ Wc,
    const float* __restrict__ bc, float* __restrict__ out, int N)
{
    int t = threadIdx.x;
    int c = t & 15;
    int n = blockIdx.x * 16 + (t >> 4);
    if (n >= N) return;
    const float* e = emb + (size_t)n * 128;
    float acc = bc[c];
    #pragma unroll 8
    for (int k = 0; k < 128; k++) acc += e[k] * Wc[k * 16 + c];
    out[(size_t)n * 16 + c] = acc;
}

static inline size_t align256(size_t x) { return (x + 255) & ~(size_t)255; }

extern "C" void kernel_launch(void* const* d_in, const int* in_sizes, int n_in,
                              void* d_out, int out_size, void* d_ws, size_t ws_size,
                              hipStream_t stream)
{
    const float* x     = (const float*)d_in[0];
    const int*   ei    = (const int*)d_in[1];
    const int*   et    = (const int*)d_in[2];
    const float* W1    = (const float*)d_in[3];
    const float* root1 = (const float*)d_in[4];
    const float* b1    = (const float*)d_in[5];
    const float* W2    = (const float*)d_in[6];
    const float* root2 = (const float*)d_in[7];
    const float* b2    = (const float*)d_in[8];
    const float* Wc    = (const float*)d_in[9];
    const float* bc    = (const float*)d_in[10];

    const int N = in_sizes[0] / 128;
    const int E = in_sizes[2];
    const int C = in_sizes[10];   // 16

    float* out = (float*)d_out;                 // [N,16]
    float* emb = out + (size_t)N * C;           // [N,128] fp32 (2nd output)

    // ws: cnt | rowptr | cursor | spk | aggX(bf16) | xb | hb | Wf1 | Wf2
    size_t cntB  = align256((size_t)NREL * N * sizeof(int));
    size_t rpB   = align256((size_t)(N + 1) * sizeof(int));
    size_t curB  = align256((size_t)N * sizeof(int));
    size_t spkB  = align256((size_t)E * sizeof(int));
    size_t aggB  = align256((size_t)NREL * N * 128 * sizeof(ushort));
    size_t xbB   = align256((size_t)N * 128 * sizeof(ushort));
    size_t wtB   = align256((size_t)128 * 1152 * sizeof(ushort));

    char* p = (char*)d_ws;
    int*    cnt    = (int*)p;      p += cntB;
    int*    rowptr = (int*)p;      p += rpB;
    int*    cursor = (int*)p;      p += curB;
    int*    spk    = (int*)p;      p += spkB;
    ushort* aggX   = (ushort*)p;   p += aggB;
    ushort* xb     = (ushort*)p;   p += xbB;
    ushort* hb     = (ushort*)p;   p += xbB;
    ushort* Wf1    = (ushort*)p;   p += wtB;
    ushort* Wf2    = (ushort*)p;

    dim3 blk(256);
    int gE    = (E + 255) / 256;
    int gN    = (N + 255) / 256;
    int gGat  = (N + 3) / 4;
    int gGemm = (N + 63) / 64;
    int gCls  = (N + 15) / 16;
    int gWt   = (128 * 1152 + 255) / 256;
    long long cnt4 = (long long)NREL * N / 4;
    int gZ = (int)((cnt4 + 255) / 256); if (gZ > 2048) gZ = 2048;
    int nx4 = N * 32;                       // N*128/4 float4 groups
    int gCx = (nx4 + 255) / 256; if (gCx > 2048) gCx = 2048;

    // ---- CSR build (shared by both layers) ----
    zero16<<<gZ, blk, 0, stream>>>((float4*)cnt, (int)cnt4);
    count_edges<<<gE, blk, 0, stream>>>(ei, et, cnt, E, N);
    dst_counts<<<gN, blk, 0, stream>>>(cnt, cursor, N);
    exscan<<<1, 1024, 0, stream>>>(cursor, rowptr, cursor, N);
    fill_csr<<<gE, blk, 0, stream>>>(ei, et, cursor, spk, E);

    // ---- bf16 conversions (weights -> fragment order) ----
    conv_x<<<gCx, blk, 0, stream>>>(x, xb, nx4);
    conv_wf<<<gWt, blk, 0, stream>>>(W1, root1, Wf1);
    conv_wf<<<gWt, blk, 0, stream>>>(W2, root2, Wf2);

    // ---- layer 1: gather + MFMA GEMM -> hb (bf16, relu) ----
    gather_aggx<<<gGat, blk, 0, stream>>>(xb, rowptr, spk, cnt, aggX, N);
    rgemm_mfma<<<gGemm, blk, 0, stream>>>(aggX, xb, Wf1, b1,
                                          nullptr, hb, N, 1);

    // ---- layer 2: gather + MFMA GEMM -> emb (fp32) ----
    gather_aggx<<<gGat, blk, 0, stream>>>(hb, rowptr, spk, cnt, aggX, N);
    rgemm_mfma<<<gGemm, blk, 0, stream>>>(aggX, hb, Wf2, b2,
                                          emb, nullptr, N, 0);

    // ---- classifier ----
    classifier<<<gCls, blk, 0, stream>>>(emb, Wc, bc, out, N);
}

// Round 11
// 353.334 us; speedup vs baseline: 37.3920x; 1.4021x over previous
//
#include <hip/hip_runtime.h>

#define NREL 8

typedef __attribute__((ext_vector_type(8))) short bf16x8;
typedef __attribute__((ext_vector_type(4))) float f32x4;

__device__ inline ushort f2bf(float f)
{
    union { float f; unsigned u; } v; v.f = f;
    unsigned r = v.u + 0x7FFF + ((v.u >> 16) & 1);   // RNE
    return (ushort)(r >> 16);
}
__device__ inline float bf2f(ushort u)
{
    union { unsigned u; float f; } v; v.u = ((unsigned)u) << 16; return v.f;
}

// ---------------------------------------------------------------------------
// zero16: graph-capturable memset replacement (round-2 lesson).
// ---------------------------------------------------------------------------
__global__ __launch_bounds__(256) void zero16(float4* __restrict__ p, int n4)
{
    int i = blockIdx.x * 256 + threadIdx.x;
    int stride = gridDim.x * 256;
    for (; i < n4; i += stride) p[i] = make_float4(0.f, 0.f, 0.f, 0.f);
}

// ---------------------------------------------------------------------------
// CSR build: count -> dst totals -> 3-kernel multi-block scan -> fill.
// (Round-9 suspicion: old single-block exscan serialized ~50k elements on
// one CU; multi-block scan uses the whole chip.)
// ---------------------------------------------------------------------------
__global__ __launch_bounds__(256) void count_edges(
    const int* __restrict__ ei, const int* __restrict__ et,
    int* __restrict__ cnt, int E, int N)
{
    int e = blockIdx.x * 256 + threadIdx.x;
    if (e < E) {
        int d = ei[E + e];
        int r = et[e];
        atomicAdd(&cnt[r * N + d], 1);
    }
}

__global__ __launch_bounds__(256) void dst_counts(
    const int* __restrict__ cnt, int* __restrict__ dcnt, int N)
{
    int d = blockIdx.x * 256 + threadIdx.x;
    if (d < N) {
        int s = 0;
        #pragma unroll
        for (int r = 0; r < NREL; r++) s += cnt[r * N + d];
        dcnt[d] = s;
    }
}

// per-block exclusive scan of 256 elems + block sum
__global__ __launch_bounds__(256) void scan1(
    const int* __restrict__ in, int* __restrict__ part,
    int* __restrict__ bsum, int n)
{
    __shared__ int tmp[256];
    int i = blockIdx.x * 256 + threadIdx.x;
    int v = (i < n) ? in[i] : 0;
    tmp[threadIdx.x] = v;
    __syncthreads();
    for (int off = 1; off < 256; off <<= 1) {
        int t = (threadIdx.x >= off) ? tmp[threadIdx.x - off] : 0;
        __syncthreads();
        tmp[threadIdx.x] += t;
        __syncthreads();
    }
    if (i < n) part[i] = tmp[threadIdx.x] - v;
    if (threadIdx.x == 255) bsum[blockIdx.x] = tmp[255];
}

// single-block exclusive scan of block sums (nb <= 1024)
__global__ __launch_bounds__(1024) void scan2(int* __restrict__ bsum, int nb)
{
    __shared__ int tmp[1024];
    int tid = threadIdx.x;
    int v = (tid < nb) ? bsum[tid] : 0;
    tmp[tid] = v;
    __syncthreads();
    for (int off = 1; off < 1024; off <<= 1) {
        int t = (tid >= off) ? tmp[tid - off] : 0;
        __syncthreads();
        tmp[tid] += t;
        __syncthreads();
    }
    if (tid < nb) bsum[tid] = tmp[tid] - v;
}

// rowptr[i] = part[i] + bsum[block];  rowptr[n] = E;  cursor = rowptr
__global__ __launch_bounds__(256) void scan3(
    const int* __restrict__ part, const int* __restrict__ bsum,
    int* __restrict__ rowptr, int* __restrict__ cursor, int n, int E)
{
    int i = blockIdx.x * 256 + threadIdx.x;
    if (i < n) {
        int v = part[i] + bsum[blockIdx.x];
        rowptr[i] = v;
        cursor[i] = v;
    }
    if (i == 0) rowptr[n] = E;
}

__global__ __launch_bounds__(256) void fill_csr(
    const int* __restrict__ ei, const int* __restrict__ et,
    int* __restrict__ cursor, int* __restrict__ spk, int E)
{
    int e = blockIdx.x * 256 + threadIdx.x;
    if (e < E) {
        int d = ei[E + e];
        int pos = atomicAdd(&cursor[d], 1);
        spk[pos] = ei[e] | (et[e] << 20);
    }
}

// ---------------------------------------------------------------------------
// conv_x: fp32 activations -> bf16, contiguous.
// ---------------------------------------------------------------------------
__global__ __launch_bounds__(256) void conv_x(
    const float* __restrict__ x, ushort* __restrict__ xb, int n4)
{
    int i = blockIdx.x * 256 + threadIdx.x;
    int stride = gridDim.x * 256;
    for (; i < n4; i += stride) {
        float4 v = ((const float4*)x)[i];
        ushort4 o;
        o.x = f2bf(v.x); o.y = f2bf(v.y); o.z = f2bf(v.z); o.w = f2bf(v.w);
        ((ushort4*)xb)[i] = o;
    }
}

// ---------------------------------------------------------------------------
// conv_wf: weights -> bf16 in MFMA-fragment order (round-9 win: wave's
// B-fragment load = 64 lanes x 16B fully contiguous, L2-resident).
// ---------------------------------------------------------------------------
__global__ __launch_bounds__(256) void conv_wf(
    const float* __restrict__ W, const float* __restrict__ root,
    ushort* __restrict__ Wf)
{
    int i = blockIdx.x * 256 + threadIdx.x;
    if (i >= 128 * 1152) return;
    int f = i >> 9;
    int within = i & 511;
    int l = within >> 3;
    int j = within & 7;
    int rs = f >> 5;
    int kk = (f >> 3) & 3;
    int n  = f & 7;
    int col = (n << 4) | (l & 15);
    int kl  = kk * 32 + (l >> 4) * 8 + j;
    float v = (rs < 8) ? W[rs * 16384 + kl * 128 + col] : root[kl * 128 + col];
    Wf[i] = f2bf(v);
}

// ---------------------------------------------------------------------------
// Gather-aggregate v2: one wave per dst.
// Round-9 diagnosis: per-edge serial load chain + DIVERGENT-compiled switch
// (compiler can't prove pk wave-uniform). Fix:
//  - one spk load covers 4 edges (lane&3), readlane -> SGPR pk
//    => scalar addresses (saddr loads) + UNIFORM s_cbranch switch
//  - 4 X-row loads batched per group => 4-deep MLP on the ~500cy chain
// ---------------------------------------------------------------------------
__global__ __launch_bounds__(256) void gather_aggx(
    const ushort* __restrict__ Xb, const int* __restrict__ rowptr,
    const int* __restrict__ spk, const int* __restrict__ cnt,
    ushort* __restrict__ aggX, int N)
{
    int w = blockIdx.x * 4 + (threadIdx.x >> 6);
    if (w >= N) return;
    int lane = threadIdx.x & 63;

    float2 a0 = {0.f, 0.f}, a1 = {0.f, 0.f}, a2 = {0.f, 0.f}, a3 = {0.f, 0.f};
    float2 a4 = {0.f, 0.f}, a5 = {0.f, 0.f}, a6 = {0.f, 0.f}, a7 = {0.f, 0.f};

    #define ROWLD(P) \
        (((const unsigned*)(Xb + (size_t)((P) & 0xFFFFF) * 128))[lane])

    #define CONSUME(P, U)                                                   \
    {                                                                       \
        float vx = bf2f((ushort)((U) & 0xFFFF));                            \
        float vy = bf2f((ushort)((U) >> 16));                               \
        switch ((P) >> 20) {                                                \
            case 0: a0.x += vx; a0.y += vy; break;                          \
            case 1: a1.x += vx; a1.y += vy; break;                          \
            case 2: a2.x += vx; a2.y += vy; break;                          \
            case 3: a3.x += vx; a3.y += vy; break;                          \
            case 4: a4.x += vx; a4.y += vy; break;                          \
            case 5: a5.x += vx; a5.y += vy; break;                          \
            case 6: a6.x += vx; a6.y += vy; break;                          \
            default: a7.x += vx; a7.y += vy; break;                         \
        }                                                                   \
    }

    int beg = rowptr[w], end = rowptr[w + 1];
    int i = beg;
    for (; i + 4 <= end; i += 4) {
        int pk4 = spk[i + (lane & 3)];
        int p0 = __builtin_amdgcn_readlane(pk4, 0);
        int p1 = __builtin_amdgcn_readlane(pk4, 1);
        int p2 = __builtin_amdgcn_readlane(pk4, 2);
        int p3 = __builtin_amdgcn_readlane(pk4, 3);
        unsigned u0 = ROWLD(p0);
        unsigned u1 = ROWLD(p1);
        unsigned u2 = ROWLD(p2);
        unsigned u3 = ROWLD(p3);
        CONSUME(p0, u0);
        CONSUME(p1, u1);
        CONSUME(p2, u2);
        CONSUME(p3, u3);
    }
    for (; i < end; i++) {
        int p = __builtin_amdgcn_readfirstlane(spk[i]);
        unsigned u = ROWLD(p);
        CONSUME(p, u);
    }
    #undef CONSUME
    #undef ROWLD

    #define WR(R, A)                                                        \
    {                                                                       \
        int c = cnt[R * N + w];                                             \
        float inv = (c > 0) ? 1.f / (float)c : 0.f;                         \
        ushort2 o; o.x = f2bf(A.x * inv); o.y = f2bf(A.y * inv);            \
        ((ushort2*)(aggX + ((size_t)R * N + w) * 128))[lane] = o;           \
    }
    WR(0, a0) WR(1, a1) WR(2, a2) WR(3, a3)
    WR(4, a4) WR(5, a5) WR(6, a6) WR(7, a7)
    #undef WR
}

// ---------------------------------------------------------------------------
// bf16 MFMA fused 9-source GEMM, LDS-free, fragment-ordered B (round-9 form).
// ---------------------------------------------------------------------------
__global__ __launch_bounds__(256) void rgemm_mfma(
    const ushort* __restrict__ aggX,   // [8][N][128] bf16
    const ushort* __restrict__ Xb,     // [N][128] bf16 (source rs=8)
    const ushort* __restrict__ Wf,     // fragment-ordered weights (294KB)
    const float* __restrict__ bias,    // [128] fp32
    float* __restrict__ Ofp,           // fp32 out (or null)
    ushort* __restrict__ Obf,          // bf16 out (or null)
    int N, int relu)
{
    int wid  = threadIdx.x >> 6;
    int lane = threadIdx.x & 63;
    int m0   = blockIdx.x * 64 + wid * 16;
    int lrow = lane & 15;
    int kgrp = lane >> 4;

    int arow = m0 + lrow;
    if (arow >= N) arow = N - 1;

    const bf16x8* Wf8 = (const bf16x8*)Wf;

    f32x4 acc[8];
    #pragma unroll
    for (int n = 0; n < 8; n++) acc[n] = (f32x4){0.f, 0.f, 0.f, 0.f};

    #pragma unroll 1
    for (int rs = 0; rs < 9; rs++) {
        const ushort* A = (rs < 8) ? aggX + ((size_t)rs * N + arow) * 128
                                   : Xb + (size_t)arow * 128;
        const bf16x8* Bp = Wf8 + (size_t)rs * 2048 + lane;

        #pragma unroll 2
        for (int kk = 0; kk < 4; kk++) {
            bf16x8 a = *(const bf16x8*)(A + kk * 32 + kgrp * 8);
            const bf16x8* bq = Bp + kk * 512;
            bf16x8 b0 = bq[0];
            bf16x8 b1 = bq[64];
            bf16x8 b2 = bq[128];
            bf16x8 b3 = bq[192];
            bf16x8 b4 = bq[256];
            bf16x8 b5 = bq[320];
            bf16x8 b6 = bq[384];
            bf16x8 b7 = bq[448];
            acc[0] = __builtin_amdgcn_mfma_f32_16x16x32_bf16(a, b0, acc[0], 0, 0, 0);
            acc[1] = __builtin_amdgcn_mfma_f32_16x16x32_bf16(a, b1, acc[1], 0, 0, 0);
            acc[2] = __builtin_amdgcn_mfma_f32_16x16x32_bf16(a, b2, acc[2], 0, 0, 0);
            acc[3] = __builtin_amdgcn_mfma_f32_16x16x32_bf16(a, b3, acc[3], 0, 0, 0);
            acc[4] = __builtin_amdgcn_mfma_f32_16x16x32_bf16(a, b4, acc[4], 0, 0, 0);
            acc[5] = __builtin_amdgcn_mfma_f32_16x16x32_bf16(a, b5, acc[5], 0, 0, 0);
            acc[6] = __builtin_amdgcn_mfma_f32_16x16x32_bf16(a, b6, acc[6], 0, 0, 0);
            acc[7] = __builtin_amdgcn_mfma_f32_16x16x32_bf16(a, b7, acc[7], 0, 0, 0);
        }
    }

    int row0 = m0 + kgrp * 4;
    #pragma unroll
    for (int n = 0; n < 8; n++) {
        int col = n * 16 + lrow;
        float bv = bias[col];
        #pragma unroll
        for (int r = 0; r < 4; r++) {
            int row = row0 + r;
            if (row >= N) continue;
            float v = acc[n][r] + bv;
            if (relu) v = fmaxf(v, 0.f);
            if (Ofp) Ofp[(size_t)row * 128 + col] = v;
            if (Obf) Obf[(size_t)row * 128 + col] = f2bf(v);
        }
    }
}

// ---------------------------------------------------------------------------
// out[n][c] = sum_k emb[n][k] * Wc[k*16+c] + bc[c];   16 nodes / block
// ---------------------------------------------------------------------------
__global__ __launch_bounds__(256) void classifier(
    const float* __restrict__ emb, const float* __restrict__ Wc,
    const float* __restrict__ bc, float* __restrict__ out, int N)
{
    int t = threadIdx.x;
    int c = t & 15;
    int n = blockIdx.x * 16 + (t >> 4);
    if (n >= N) return;
    const float* e = emb + (size_t)n * 128;
    float acc = bc[c];
    #pragma unroll 8
    for (int k = 0; k < 128; k++) acc += e[k] * Wc[k * 16 + c];
    out[(size_t)n * 16 + c] = acc;
}

static inline size_t align256(size_t x) { return (x + 255) & ~(size_t)255; }

extern "C" void kernel_launch(void* const* d_in, const int* in_sizes, int n_in,
                              void* d_out, int out_size, void* d_ws, size_t ws_size,
                              hipStream_t stream)
{
    const float* x     = (const float*)d_in[0];
    const int*   ei    = (const int*)d_in[1];
    const int*   et    = (const int*)d_in[2];
    const float* W1    = (const float*)d_in[3];
    const float* root1 = (const float*)d_in[4];
    const float* b1    = (const float*)d_in[5];
    const float* W2    = (const float*)d_in[6];
    const float* root2 = (const float*)d_in[7];
    const float* b2    = (const float*)d_in[8];
    const float* Wc    = (const float*)d_in[9];
    const float* bc    = (const float*)d_in[10];

    const int N = in_sizes[0] / 128;
    const int E = in_sizes[2];
    const int C = in_sizes[10];   // 16

    float* out = (float*)d_out;                 // [N,16]
    float* emb = out + (size_t)N * C;           // [N,128] fp32 (2nd output)

    // ws: cnt | rowptr | cursor | part | bsum | spk | aggX | xb | hb | Wf1 | Wf2
    size_t cntB  = align256((size_t)NREL * N * sizeof(int));
    size_t rpB   = align256((size_t)(N + 1) * sizeof(int));
    size_t curB  = align256((size_t)N * sizeof(int));
    size_t bsB   = align256((size_t)1024 * sizeof(int));
    size_t spkB  = align256((size_t)E * sizeof(int));
    size_t aggB  = align256((size_t)NREL * N * 128 * sizeof(ushort));
    size_t xbB   = align256((size_t)N * 128 * sizeof(ushort));
    size_t wtB   = align256((size_t)128 * 1152 * sizeof(ushort));

    char* p = (char*)d_ws;
    int*    cnt    = (int*)p;      p += cntB;
    int*    rowptr = (int*)p;      p += rpB;
    int*    cursor = (int*)p;      p += curB;
    int*    part   = (int*)p;      p += curB;
    int*    bsum   = (int*)p;      p += bsB;
    int*    spk    = (int*)p;      p += spkB;
    ushort* aggX   = (ushort*)p;   p += aggB;
    ushort* xb     = (ushort*)p;   p += xbB;
    ushort* hb     = (ushort*)p;   p += xbB;
    ushort* Wf1    = (ushort*)p;   p += wtB;
    ushort* Wf2    = (ushort*)p;

    dim3 blk(256);
    int gE    = (E + 255) / 256;
    int gN    = (N + 255) / 256;     // 196 blocks (<=1024 for scan2)
    int gGat  = (N + 3) / 4;
    int gGemm = (N + 63) / 64;
    int gCls  = (N + 15) / 16;
    int gWt   = (128 * 1152 + 255) / 256;
    long long cnt4 = (long long)NREL * N / 4;
    int gZ = (int)((cnt4 + 255) / 256); if (gZ > 2048) gZ = 2048;
    int nx4 = N * 32;
    int gCx = (nx4 + 255) / 256; if (gCx > 2048) gCx = 2048;

    // ---- CSR build (shared by both layers) ----
    zero16<<<gZ, blk, 0, stream>>>((float4*)cnt, (int)cnt4);
    count_edges<<<gE, blk, 0, stream>>>(ei, et, cnt, E, N);
    dst_counts<<<gN, blk, 0, stream>>>(cnt, cursor, N);          // cursor = dcnt
    scan1<<<gN, blk, 0, stream>>>(cursor, part, bsum, N);
    scan2<<<1, 1024, 0, stream>>>(bsum, gN);
    scan3<<<gN, blk, 0, stream>>>(part, bsum, rowptr, cursor, N, E);
    fill_csr<<<gE, blk, 0, stream>>>(ei, et, cursor, spk, E);

    // ---- bf16 conversions ----
    conv_x<<<gCx, blk, 0, stream>>>(x, xb, nx4);
    conv_wf<<<gWt, blk, 0, stream>>>(W1, root1, Wf1);
    conv_wf<<<gWt, blk, 0, stream>>>(W2, root2, Wf2);

    // ---- layer 1: gather + MFMA GEMM -> hb (bf16, relu) ----
    gather_aggx<<<gGat, blk, 0, stream>>>(xb, rowptr, spk, cnt, aggX, N);
    rgemm_mfma<<<gGemm, blk, 0, stream>>>(aggX, xb, Wf1, b1,
                                          nullptr, hb, N, 1);

    // ---- layer 2: gather + MFMA GEMM -> emb (fp32) ----
    gather_aggx<<<gGat, blk, 0, stream>>>(hb, rowptr, spk, cnt, aggX, N);
    rgemm_mfma<<<gGemm, blk, 0, stream>>>(aggX, hb, Wf2, b2,
                                          emb, nullptr, N, 0);

    // ---- classifier ----
    classifier<<<gCls, blk, 0, stream>>>(emb, Wc, bc, out, N);
}